// Round 12
// baseline (998.579 us; speedup 1.0000x reference)
//
#include <hip/hip_runtime.h>
#include <stdint.h>

#define NN 50000
#define EE 400000
#define TT 7
#define LN_EPS 1e-5f
#define SIG_SC (-1.4426950408889634f)   // -log2(e): sigmoid prescale
#define TANH_SC (2.8853900817779268f)   // +2*log2(e): tanh prescale

typedef __attribute__((ext_vector_type(8))) short bf16x8;
typedef __attribute__((ext_vector_type(4))) float f32x4;

__device__ __forceinline__ float leaky01(float x){ return x > 0.f ? x : 0.01f*x; }
__device__ __forceinline__ float fastrcp(float x){ return __builtin_amdgcn_rcpf(x); }
__device__ __forceinline__ float exp2fast(float x){ return __builtin_amdgcn_exp2f(x); }
__device__ __forceinline__ unsigned bf16rne(float f){
  unsigned u = __float_as_uint(f);
  return (u + 0x7fffu + ((u>>16)&1u)) >> 16;
}
__device__ __forceinline__ float bfu(unsigned u){ return __uint_as_float(u<<16); }
__device__ __forceinline__ float bfhi(unsigned u){ return __uint_as_float(u & 0xffff0000u); }

// ---------------- one-shot prep: weight packing + inits + x->bf16 ----------------
__global__ __launch_bounds__(256) void k_prep_all(
    const float* __restrict__ Wih0, const float* __restrict__ Whh0,
    const float* __restrict__ Wih1, const float* __restrict__ Whh1,
    const float* __restrict__ Wg2,
    const float* __restrict__ bih0, const float* __restrict__ bhh0,
    const float* __restrict__ bih1, const float* __restrict__ bhh1,
    const float* __restrict__ Wm1, const float* __restrict__ Wd1,
    const float* __restrict__ x,
    uint4* __restrict__ WF, uint4* __restrict__ WG2F, uint4* __restrict__ WHF,
    float* __restrict__ BS,
    ushort* __restrict__ xb, float* __restrict__ deg, int* __restrict__ counts){
  int b = blockIdx.x, tid = threadIdx.x;
  if (b < 32){
    int idx = b*256 + tid;
    int L = idx >> 12;
    int r = idx & 4095;
    int lane = r & 63;
    int e = r >> 6;
    int which = e & 1;
    int cs = e >> 1;
    int s = cs & 1, ct = cs >> 1;
    int row = ct*16 + (lane & 15);
    float sc = ((row >> 6) == 2) ? TANH_SC : SIG_SC;
    int kb = s*32 + (lane >> 4)*8;
    const float* W = L ? (which ? Whh1 : Wih1) : (which ? Whh0 : Wih0);
    const float* p = W + row*64 + kb;
    uint4 v;
    v.x = bf16rne(sc*p[0]) | (bf16rne(sc*p[1])<<16);
    v.y = bf16rne(sc*p[2]) | (bf16rne(sc*p[3])<<16);
    v.z = bf16rne(sc*p[4]) | (bf16rne(sc*p[5])<<16);
    v.w = bf16rne(sc*p[6]) | (bf16rne(sc*p[7])<<16);
    WF[idx] = v;
  } else if (b < 34){
    int idx = (b-32)*256 + tid;   // 0..511
    int lane = idx & 63, e = idx >> 6;   // e = ct*2+s
    int s = e & 1, ct = e >> 1;
    int kb = s*32 + (lane>>4)*8;
    int c = ct*16 + (lane&15);
    uint4 v;
    v.x = bf16rne(Wg2[(kb+0)*64+c]) | (bf16rne(Wg2[(kb+1)*64+c])<<16);
    v.y = bf16rne(Wg2[(kb+2)*64+c]) | (bf16rne(Wg2[(kb+3)*64+c])<<16);
    v.z = bf16rne(Wg2[(kb+4)*64+c]) | (bf16rne(Wg2[(kb+5)*64+c])<<16);
    v.w = bf16rne(Wg2[(kb+6)*64+c]) | (bf16rne(Wg2[(kb+7)*64+c])<<16);
    WG2F[idx] = v;
  } else if (b < 36){
    int L = b - 34;
    float sc = ((tid >> 6) == 2) ? TANH_SC : SIG_SC;
    BS[L*256+tid] = sc * (L ? (bih1[tid]+bhh1[tid]) : (bih0[tid]+bhh0[tid]));
  } else if (b < 38){
    int idx = (b-36)*256 + tid;   // 0..383 used
    if (idx < 384){
      int lane = idx & 63, e = idx >> 6;   // e = ct*2+s, ct in 0..2
      int s = e & 1, ct = e >> 1;
      int kb = s*32 + (lane>>4)*8;
      int c = ct*16 + (lane&15);
      float w[8];
      #pragma unroll
      for (int j = 0; j < 8; ++j)
        w[j] = (c < 32) ? Wm1[(kb+j)*32 + c] : Wd1[(kb+j)*16 + (c-32)];
      uint4 v;
      v.x = bf16rne(w[0]) | (bf16rne(w[1])<<16);
      v.y = bf16rne(w[2]) | (bf16rne(w[3])<<16);
      v.z = bf16rne(w[4]) | (bf16rne(w[5])<<16);
      v.w = bf16rne(w[6]) | (bf16rne(w[7])<<16);
      WHF[idx] = v;
    }
  } else if (b < 234){
    int i = (b-38)*256 + tid;
    if (i < NN){ deg[i] = 1.0f; counts[i] = 0; }
  } else {
    int i = (b-234)*256 + tid;
    if (i < NN*49) xb[i] = (ushort)bf16rne(x[i]);
  }
}

// ---------------- graph norm / CSR build ----------------
__global__ void k_edge_count(const int* __restrict__ src, const int* __restrict__ dst,
                             const float* __restrict__ ew, float* deg, int* counts){
  int e = blockIdx.x*blockDim.x + threadIdx.x;
  if (e < EE){
    int d = dst[e];
    atomicAdd(&deg[d], ew[e]);
    atomicAdd(&counts[d], 1);
  }
}
__global__ __launch_bounds__(256) void k_scan_blk(const int* __restrict__ counts,
                                                  int* locincl, int* bsum, float* deg){
  int tid = threadIdx.x; int i = blockIdx.x*256 + tid;
  if (i < NN) deg[i] = rsqrtf(deg[i]);      // deg >= 1 always
  int v = (i < NN) ? counts[i] : 0;
  int lane = tid & 63;
  int val = v;
  #pragma unroll
  for (int off = 1; off < 64; off <<= 1){
    int u = __shfl_up(val, off, 64);
    if (lane >= off) val += u;
  }
  __shared__ int wsum[4];
  if (lane == 63) wsum[tid>>6] = val;
  __syncthreads();
  int w = tid >> 6, pre = 0;
  #pragma unroll
  for (int k = 0; k < 4; ++k) if (k < w) pre += wsum[k];
  int incl = val + pre;
  if (i < NN) locincl[i] = incl;
  if (tid == 255) bsum[blockIdx.x] = incl;
}
// fixup with the 196-wide top-scan inlined (every block redoes it; saves a dispatch)
__global__ __launch_bounds__(256) void k_scan_fix(const int* __restrict__ locincl,
        const int* __restrict__ bsum, const int* __restrict__ counts,
        int* rowptr, int* cursor){
  __shared__ int sb[256];
  __shared__ int wsum[4];
  int tid = threadIdx.x;
  int v = (tid < 196) ? bsum[tid] : 0;
  int lane = tid & 63;
  int val = v;
  #pragma unroll
  for (int off = 1; off < 64; off <<= 1){
    int u = __shfl_up(val, off, 64);
    if (lane >= off) val += u;
  }
  if (lane == 63) wsum[tid>>6] = val;
  __syncthreads();
  int w = tid >> 6, pre = 0;
  #pragma unroll
  for (int k = 0; k < 4; ++k) if (k < w) pre += wsum[k];
  sb[tid] = val + pre;     // inclusive scan of bsum
  __syncthreads();
  int boff = (blockIdx.x == 0) ? 0 : sb[blockIdx.x - 1];
  int i = blockIdx.x*256 + tid;
  if (i < NN){
    int r = locincl[i] + boff;
    rowptr[i+1] = r;
    cursor[i] = r - counts[i];
  }
  if (i == 0) rowptr[0] = 0;
}
__global__ void k_scatter(const int* __restrict__ src, const int* __restrict__ dst,
                          const float* __restrict__ ew, const float* __restrict__ dinv,
                          int* cursor, uint2* e2){
  int e = blockIdx.x*blockDim.x + threadIdx.x;
  if (e < EE){
    int s = src[e], d = dst[e];
    float nv = dinv[s]*ew[e]*dinv[d];
    int slot = atomicAdd(&cursor[d], 1);
    e2[slot] = make_uint2((uint)s, __float_as_uint(nv));
  }
}

// ---------------- GCN ----------------
// agg_x: 1 node per wave (full gather parallelism — the thing round 11 broke)
__global__ __launch_bounds__(256) void k_agg_x(const ushort* __restrict__ xb,
        const float* __restrict__ dinv, const int* __restrict__ rowptr,
        const uint2* __restrict__ e2, float* __restrict__ AX){
  int lane = threadIdx.x & 63, w = threadIdx.x >> 6;
  int i = blockIdx.x*4 + w;
  int beg = rowptr[i], end = rowptr[i+1];
  float di = dinv[i];
  float acc = 0.f;
  if (lane < 49) acc = di*di*bfu(xb[(size_t)i*49 + lane]);
  for (int s = beg; s < end; ++s){
    uint2 e = e2[s];
    int cs = (int)e.x; float wv = __uint_as_float(e.y);
    if (lane < 49) acc += wv * bfu(xb[(size_t)cs*49 + lane]);
  }
  if (lane < 49) AX[(size_t)i*49 + lane] = acc;
}
__global__ __launch_bounds__(256) void k_gcn2_mfma(const float* __restrict__ AX,
        const float* __restrict__ Wg1, const float* __restrict__ bg1,
        const uint4* __restrict__ WG2F, ushort* __restrict__ Z2p){
  __shared__ float sw1[448];
  __shared__ float sb1[64];
  __shared__ float sax[8*56];
  __shared__ __align__(16) ushort srb[64*68];
  int tid = threadIdx.x;
  int lane = tid & 63, w = tid >> 6;
  bf16x8 bw[4][2];
  #pragma unroll
  for (int ct = 0; ct < 4; ++ct)
    #pragma unroll
    for (int s = 0; s < 2; ++s){
      uint4 v = WG2F[(ct*2+s)*64 + lane];
      bw[ct][s] = *(bf16x8*)&v;
    }
  for (int i = tid; i < 448; i += 256) sw1[i] = Wg1[i];
  if (tid < 64) sb1[tid] = bg1[tid];
  int nbase = blockIdx.x*8;
  for (int i = tid; i < 448; i += 256){
    int n = i/56, c = i%56;
    sax[i] = (c < 49) ? AX[(size_t)(nbase+n)*49 + c] : 0.f;
  }
  __syncthreads();
  {
    int node = lane >> 3, t = lane & 7;
    float a[7];
    #pragma unroll
    for (int kk = 0; kk < 7; ++kk) a[kk] = sax[node*56 + t*7 + kk];
    ushort hv[16];
    #pragma unroll
    for (int j = 0; j < 16; ++j){
      int k = w*16 + j;
      float acc = sb1[k];
      #pragma unroll
      for (int kk = 0; kk < 7; ++kk) acc += a[kk]*sw1[kk*64+k];
      hv[j] = (ushort)bf16rne(leaky01(acc));
    }
    uint2* dst = (uint2*)&srb[lane*68 + w*16];
    #pragma unroll
    for (int q = 0; q < 4; ++q){
      uint2 v;
      v.x = (uint)hv[q*4+0] | ((uint)hv[q*4+1]<<16);
      v.y = (uint)hv[q*4+2] | ((uint)hv[q*4+3]<<16);
      dst[q] = v;
    }
  }
  __syncthreads();
  int col = lane & 15, quad = lane >> 4;
  bf16x8 afr[2];
  #pragma unroll
  for (int s = 0; s < 2; ++s){
    const ushort* pr = &srb[(w*16 + col)*68 + s*32 + quad*8];
    uint2 lo = *(const uint2*)pr;
    uint2 hi = *(const uint2*)(pr + 4);
    union { uint u[4]; bf16x8 b; } cv;
    cv.u[0]=lo.x; cv.u[1]=lo.y; cv.u[2]=hi.x; cv.u[3]=hi.y;
    afr[s] = cv.b;
  }
  f32x4 acc[4];
  #pragma unroll
  for (int ct = 0; ct < 4; ++ct) acc[ct] = (f32x4){0.f,0.f,0.f,0.f};
  #pragma unroll
  for (int ct = 0; ct < 4; ++ct)
    #pragma unroll
    for (int s = 0; s < 2; ++s)
      acc[ct] = __builtin_amdgcn_mfma_f32_16x16x32_bf16(afr[s], bw[ct][s], acc[ct], 0,0,0);
  int node = nbase + w*2 + (quad>>1);
  #pragma unroll
  for (int ct = 0; ct < 4; ++ct){
    uint2 v;
    v.x = bf16rne(acc[ct][0]) | (bf16rne(acc[ct][1])<<16);
    v.y = bf16rne(acc[ct][2]) | (bf16rne(acc[ct][3])<<16);
    size_t o = ((size_t)node*64 + ct*16 + col)*8 + (quad&1)*4;
    *(uint2*)(Z2p + o) = v;
  }
}

// ---------------- fused: agg+LN (1 node/wave) -> LSTM (waves 0-3) -> heads ----------------
// 512 threads = 8 waves, 8 nodes/block. Gather keeps full MLP (50k waves device-wide);
// LSTM uses the verified transposed-MFMA scheme on 16-col tiles (cols 8-15 junk,
// confined by per-column MFMA independence; zero-initialized so junk stays finite).
// Blocks in gather phase overlap blocks in LSTM phase per CU (mem vs VALU pipes).
__global__ __launch_bounds__(512, 6) void k_agg_lstm(const ushort* __restrict__ Z2p_,
        const float* __restrict__ dinv, const int* __restrict__ rowptr,
        const uint2* __restrict__ e2,
        const float* __restrict__ bg2, const float* __restrict__ lng,
        const float* __restrict__ lnb,
        const uint4* __restrict__ WF, const float* __restrict__ BS,
        const uint4* __restrict__ WHF,
        const float* __restrict__ bm1, const float* __restrict__ bd1,
        const float* __restrict__ Wm2, const float* __restrict__ bm2,
        const float* __restrict__ Wd2, const float* __restrict__ bd2,
        float* __restrict__ out){
  __shared__ __align__(16) ushort XL[7][16][72];   // 15.75 KB
  int tid = threadIdx.x;
  int lane = tid & 63, wv = tid >> 6;              // 8 waves
  int base = blockIdx.x*8;
  int col = lane & 15, quad = lane >> 4;

  // ---- phase 1: wave wv gathers + LNs node base+wv; zeroes pad row wv+8 ----
  {
    const uint4* zp = (const uint4*)Z2p_;
    int i = base + wv;
    float acc[7] = {0.f,0.f,0.f,0.f,0.f,0.f,0.f};
    if (i < NN){
      int beg = rowptr[i], end = rowptr[i+1];
      float di = dinv[i];
      float swt = di*di;
      uint4 v = zp[(size_t)i*64 + lane];
      acc[0] = swt*bfu(v.x); acc[1] = swt*bfhi(v.x);
      acc[2] = swt*bfu(v.y); acc[3] = swt*bfhi(v.y);
      acc[4] = swt*bfu(v.z); acc[5] = swt*bfhi(v.z);
      acc[6] = swt*bfu(v.w);
      for (int s = beg; s < end; ++s){
        uint2 e = e2[s];
        float wvv = __uint_as_float(e.y);
        uint4 vv = zp[(size_t)e.x*64 + lane];
        acc[0] = fmaf(wvv, bfu(vv.x),  acc[0]);
        acc[1] = fmaf(wvv, bfhi(vv.x), acc[1]);
        acc[2] = fmaf(wvv, bfu(vv.y),  acc[2]);
        acc[3] = fmaf(wvv, bfhi(vv.y), acc[3]);
        acc[4] = fmaf(wvv, bfu(vv.z),  acc[4]);
        acc[5] = fmaf(wvv, bfhi(vv.z), acc[5]);
        acc[6] = fmaf(wvv, bfu(vv.w),  acc[6]);
      }
    }
    float b2 = bg2[lane], gl = lng[lane], bl = lnb[lane];
    #pragma unroll
    for (int t = 0; t < 7; ++t){
      float a = leaky01(acc[t] + b2);
      float sum = a;
      #pragma unroll
      for (int off = 32; off >= 1; off >>= 1) sum += __shfl_xor(sum, off, 64);
      float mu = sum * (1.f/64.f);
      float d = a - mu;
      float vs = d*d;
      #pragma unroll
      for (int off = 32; off >= 1; off >>= 1) vs += __shfl_xor(vs, off, 64);
      float rs = rsqrtf(vs*(1.f/64.f) + LN_EPS);
      XL[t][wv][lane] = (ushort)bf16rne(d*rs*gl + bl);
      XL[t][wv+8][lane] = 0;
    }
  }
  __syncthreads();

  // ---- phase 2: LSTM (transposed MFMA), waves 0-3 active; 4-7 barrier-only ----
  int cp = wv & 3;
  bool act = (wv < 4);
  bf16x8 hfr[2];
  for (int L = 0; L < 2; ++L){
    bf16x8 bwi[4][2], bwh[4][2];
    f32x4 bias4[4];
    if (act){
      const uint4* wf = WF + L*4096;
      #pragma unroll
      for (int g = 0; g < 4; ++g){
        int ct = cp + 4*g;
        #pragma unroll
        for (int s = 0; s < 2; ++s){
          uint4 wi = wf[((ct*2+s)*2+0)*64 + lane];
          uint4 wh = wf[((ct*2+s)*2+1)*64 + lane];
          bwi[g][s] = *(bf16x8*)&wi;
          bwh[g][s] = *(bf16x8*)&wh;
        }
      }
      #pragma unroll
      for (int g = 0; g < 4; ++g)
        bias4[g] = *(const f32x4*)&BS[L*256 + (cp + 4*g)*16 + quad*4];
    }
    f32x4 cst = (f32x4){0.f,0.f,0.f,0.f};
    hfr[0] = (bf16x8){0,0,0,0,0,0,0,0};
    hfr[1] = (bf16x8){0,0,0,0,0,0,0,0};

    for (int t = 0; t < 7; ++t){
      f32x4 acc[4];
      if (act){
        bf16x8 ax[2];
        #pragma unroll
        for (int s = 0; s < 2; ++s)
          ax[s] = *(const bf16x8*)&XL[t][col][s*32 + quad*8];
        #pragma unroll
        for (int g = 0; g < 4; ++g) acc[g] = bias4[g];
        #pragma unroll
        for (int g = 0; g < 4; ++g){
          #pragma unroll
          for (int s = 0; s < 2; ++s){
            acc[g] = __builtin_amdgcn_mfma_f32_16x16x32_bf16(bwi[g][s], ax[s], acc[g], 0,0,0);
            acc[g] = __builtin_amdgcn_mfma_f32_16x16x32_bf16(bwh[g][s], hfr[s], acc[g], 0,0,0);
          }
        }
      }
      __syncthreads();   // all reads of plane t done before overwrite
      if (act){
        ushort hv[4];
        #pragma unroll
        for (int r = 0; r < 4; ++r){
          float ig = fastrcp(1.f + exp2fast(acc[0][r]));
          float fg = fastrcp(1.f + exp2fast(acc[1][r]));
          float gg = fmaf(-2.f, fastrcp(1.f + exp2fast(acc[2][r])), 1.f);
          float og = fastrcp(1.f + exp2fast(acc[3][r]));
          float cn = fmaf(fg, cst[r], ig*gg);
          cst[r] = cn;
          float tc = fmaf(-2.f, fastrcp(1.f + exp2fast(TANH_SC*cn)), 1.f);
          hv[r] = (ushort)bf16rne(og*tc);
        }
        uint2 hw;
        hw.x = (uint)hv[0] | ((uint)hv[1]<<16);
        hw.y = (uint)hv[2] | ((uint)hv[3]<<16);
        *(uint2*)&XL[t][col][cp*16 + quad*4] = hw;
      }
      __syncthreads();
      if (act){
        hfr[0] = *(const bf16x8*)&XL[t][col][quad*8];
        hfr[1] = *(const bf16x8*)&XL[t][col][32 + quad*8];
      }
    }
  }
  // ---- heads: hfr = final h1 frags. First layer (64->48) via swapped MFMA. ----
  float* SH1 = (float*)&XL[0][0][0];   // planes 0-1 dead; [16][52] = 3.3 KB
  if (wv < 3){
    uint4 w0 = WHF[(wv*2+0)*64 + lane];
    uint4 w1 = WHF[(wv*2+1)*64 + lane];
    f32x4 hacc = (f32x4){0.f,0.f,0.f,0.f};
    hacc = __builtin_amdgcn_mfma_f32_16x16x32_bf16(*(bf16x8*)&w0, hfr[0], hacc, 0,0,0);
    hacc = __builtin_amdgcn_mfma_f32_16x16x32_bf16(*(bf16x8*)&w1, hfr[1], hacc, 0,0,0);
    float sv[4];
    #pragma unroll
    for (int r = 0; r < 4; ++r){
      int c = wv*16 + quad*4 + r;
      float b = (wv < 2) ? bm1[c] : bd1[c - 32];
      float v = hacc[r] + b;
      sv[r] = (wv < 2) ? leaky01(v) : fmaxf(v, 0.f);
    }
    *(float4*)&SH1[col*52 + wv*16 + quad*4] = make_float4(sv[0], sv[1], sv[2], sv[3]);
  }
  __syncthreads();
  // ---- second layer: 16 threads/node, shfl-reduce over the 16-lane group ----
  int node = tid >> 4, sub = tid & 15;
  if (node < 8){
    int gn = base + node;
    float m1a = SH1[node*52 + sub];
    float m1b = SH1[node*52 + 16 + sub];
    float d1v = SH1[node*52 + 32 + sub];
    float4 wa = *(const float4*)&Wm2[sub*4];
    float4 wb = *(const float4*)&Wm2[(sub+16)*4];
    float4 wc = *(const float4*)&Wd2[sub*4];
    float pm0 = m1a*wa.x + m1b*wb.x, pm1 = m1a*wa.y + m1b*wb.y;
    float pm2 = m1a*wa.z + m1b*wb.z, pm3 = m1a*wa.w + m1b*wb.w;
    float pd0 = d1v*wc.x, pd1 = d1v*wc.y, pd2 = d1v*wc.z, pd3 = d1v*wc.w;
    #pragma unroll
    for (int off = 1; off < 16; off <<= 1){
      pm0 += __shfl_xor(pm0, off, 16); pm1 += __shfl_xor(pm1, off, 16);
      pm2 += __shfl_xor(pm2, off, 16); pm3 += __shfl_xor(pm3, off, 16);
      pd0 += __shfl_xor(pd0, off, 16); pd1 += __shfl_xor(pd1, off, 16);
      pd2 += __shfl_xor(pd2, off, 16); pd3 += __shfl_xor(pd3, off, 16);
    }
    if (sub < 4 && gn < NN){
      float mo = (sub==0)?pm0:(sub==1)?pm1:(sub==2)?pm2:pm3;
      float dv = (sub==0)?pd0:(sub==1)?pd1:(sub==2)?pd2:pd3;
      mo += bm2[sub]; dv += bd2[sub];
      out[(size_t)gn*4 + sub] = fmaxf(mo, 0.f) + 1e-4f;
      out[(size_t)NN*4 + (size_t)gn*4 + sub] = dv;
    }
  }
}

extern "C" void kernel_launch(void* const* d_in, const int* in_sizes, int n_in,
                              void* d_out, int out_size, void* d_ws, size_t ws_size,
                              hipStream_t stream){
  const float* x    = (const float*)d_in[0];
  const int*   eidx = (const int*)d_in[1];
  const float* ew   = (const float*)d_in[2];
  const float* Wg1  = (const float*)d_in[3];
  const float* bg1  = (const float*)d_in[4];
  const float* Wg2  = (const float*)d_in[5];
  const float* bg2  = (const float*)d_in[6];
  const float* lng  = (const float*)d_in[7];
  const float* lnb  = (const float*)d_in[8];
  const float* Wih0 = (const float*)d_in[9];
  const float* Whh0 = (const float*)d_in[10];
  const float* bih0 = (const float*)d_in[11];
  const float* bhh0 = (const float*)d_in[12];
  const float* Wih1 = (const float*)d_in[13];
  const float* Whh1 = (const float*)d_in[14];
  const float* bih1 = (const float*)d_in[15];
  const float* bhh1 = (const float*)d_in[16];
  const float* Wm1  = (const float*)d_in[17];
  const float* bm1  = (const float*)d_in[18];
  const float* Wm2  = (const float*)d_in[19];
  const float* bm2  = (const float*)d_in[20];
  const float* Wd1  = (const float*)d_in[21];
  const float* bd1  = (const float*)d_in[22];
  const float* Wd2  = (const float*)d_in[23];
  const float* bd2  = (const float*)d_in[24];
  const int* src = eidx;
  const int* dst = eidx + EE;
  float* out = (float*)d_out;

  char* p = (char*)d_ws;
  auto alloc = [&](size_t bytes)->char*{ char* r = p; p += (bytes + 255) & ~(size_t)255; return r; };
  float*  deg     = (float*)alloc((size_t)NN*4);       // becomes dinv
  int*    counts  = (int*)  alloc((size_t)NN*4);
  int*    rowptr  = (int*)  alloc((size_t)(NN+1)*4);
  int*    cursor  = (int*)  alloc((size_t)NN*4);
  int*    locincl = (int*)  alloc((size_t)NN*4);
  int*    bsum    = (int*)  alloc((size_t)256*4);
  uint2*  e2      = (uint2*)alloc((size_t)EE*8);
  uint4*  WF      = (uint4*)alloc((size_t)2*4096*16);
  uint4*  WG2F    = (uint4*)alloc((size_t)512*16);
  uint4*  WHF     = (uint4*)alloc((size_t)384*16);
  float*  BS      = (float*)alloc((size_t)2*256*4);
  ushort* xb      = (ushort*)alloc((size_t)NN*49*2);
  float*  AX      = (float*)alloc((size_t)NN*49*4);
  ushort* Z2p     = (ushort*)alloc((size_t)NN*64*8*2);

  int xblocks = (NN*49 + 255)/256;                 // 9571
  k_prep_all<<<234 + xblocks, 256, 0, stream>>>(Wih0, Whh0, Wih1, Whh1, Wg2,
      bih0, bhh0, bih1, bhh1, Wm1, Wd1, x, WF, WG2F, WHF, BS, xb, deg, counts);
  k_edge_count<<<(EE+255)/256, 256, 0, stream>>>(src, dst, ew, deg, counts);
  k_scan_blk<<<196, 256, 0, stream>>>(counts, locincl, bsum, deg);
  k_scan_fix<<<196, 256, 0, stream>>>(locincl, bsum, counts, rowptr, cursor);
  k_scatter<<<(EE+255)/256, 256, 0, stream>>>(src, dst, ew, deg, cursor, e2);
  k_agg_x<<<NN/4, 256, 0, stream>>>(xb, deg, rowptr, e2, AX);
  k_gcn2_mfma<<<NN/8, 256, 0, stream>>>(AX, Wg1, bg1, WG2F, Z2p);
  k_agg_lstm<<<NN/8, 512, 0, stream>>>(Z2p, deg, rowptr, e2, bg2, lng, lnb,
      WF, BS, WHF, bm1, bd1, Wm2, bm2, Wd2, bd2, out);
}

// Round 13
// 401.459 us; speedup vs baseline: 2.4874x; 2.4874x over previous
//
#include <hip/hip_runtime.h>
#include <stdint.h>

#define NN 50000
#define NP 50048          // padded to 64 for the MFMA LSTM kernel
#define EE 400000
#define TT 7
#define LN_EPS 1e-5f
#define SIG_SC (-1.4426950408889634f)   // -log2(e): sigmoid prescale
#define TANH_SC (2.8853900817779268f)   // +2*log2(e): tanh prescale

typedef __attribute__((ext_vector_type(8))) short bf16x8;
typedef __attribute__((ext_vector_type(4))) float f32x4;

__device__ __forceinline__ float leaky01(float x){ return x > 0.f ? x : 0.01f*x; }
__device__ __forceinline__ float fastrcp(float x){ return __builtin_amdgcn_rcpf(x); }
__device__ __forceinline__ float exp2fast(float x){ return __builtin_amdgcn_exp2f(x); }
__device__ __forceinline__ unsigned bf16rne(float f){
  unsigned u = __float_as_uint(f);
  return (u + 0x7fffu + ((u>>16)&1u)) >> 16;
}
__device__ __forceinline__ float bfu(unsigned u){ return __uint_as_float(u<<16); }
__device__ __forceinline__ float bfhi(unsigned u){ return __uint_as_float(u & 0xffff0000u); }

// ---------------- one-shot prep: weight packing + inits + x->bf16 ----------------
// LSTM weights/biases PRE-SCALED: i/f/o rows * SIG_SC, g rows * TANH_SC.
// Fragment packings valid for BOTH operand orders (A-frag [m=lane&15][k=quad*8+j]
// and B-frag [k=quad*8+j][n=lane&15] share the same memory mapping).
__global__ __launch_bounds__(256) void k_prep_all(
    const float* __restrict__ Wih0, const float* __restrict__ Whh0,
    const float* __restrict__ Wih1, const float* __restrict__ Whh1,
    const float* __restrict__ Wg2,
    const float* __restrict__ bih0, const float* __restrict__ bhh0,
    const float* __restrict__ bih1, const float* __restrict__ bhh1,
    const float* __restrict__ Wm1, const float* __restrict__ Wd1,
    const float* __restrict__ x,
    uint4* __restrict__ WF, uint4* __restrict__ WG2F, uint4* __restrict__ WHF,
    float* __restrict__ BS,
    ushort* __restrict__ xb, float* __restrict__ deg, int* __restrict__ counts){
  int b = blockIdx.x, tid = threadIdx.x;
  if (b < 32){
    int idx = b*256 + tid;
    int L = idx >> 12;
    int r = idx & 4095;
    int lane = r & 63;
    int e = r >> 6;
    int which = e & 1;
    int cs = e >> 1;
    int s = cs & 1, ct = cs >> 1;
    int row = ct*16 + (lane & 15);
    float sc = ((row >> 6) == 2) ? TANH_SC : SIG_SC;
    int kb = s*32 + (lane >> 4)*8;
    const float* W = L ? (which ? Whh1 : Wih1) : (which ? Whh0 : Wih0);
    const float* p = W + row*64 + kb;
    uint4 v;
    v.x = bf16rne(sc*p[0]) | (bf16rne(sc*p[1])<<16);
    v.y = bf16rne(sc*p[2]) | (bf16rne(sc*p[3])<<16);
    v.z = bf16rne(sc*p[4]) | (bf16rne(sc*p[5])<<16);
    v.w = bf16rne(sc*p[6]) | (bf16rne(sc*p[7])<<16);
    WF[idx] = v;
  } else if (b < 34){
    int idx = (b-32)*256 + tid;   // 0..511
    int lane = idx & 63, e = idx >> 6;   // e = ct*2+s
    int s = e & 1, ct = e >> 1;
    int kb = s*32 + (lane>>4)*8;
    int c = ct*16 + (lane&15);
    uint4 v;
    v.x = bf16rne(Wg2[(kb+0)*64+c]) | (bf16rne(Wg2[(kb+1)*64+c])<<16);
    v.y = bf16rne(Wg2[(kb+2)*64+c]) | (bf16rne(Wg2[(kb+3)*64+c])<<16);
    v.z = bf16rne(Wg2[(kb+4)*64+c]) | (bf16rne(Wg2[(kb+5)*64+c])<<16);
    v.w = bf16rne(Wg2[(kb+6)*64+c]) | (bf16rne(Wg2[(kb+7)*64+c])<<16);
    WG2F[idx] = v;
  } else if (b < 36){
    int L = b - 34;
    float sc = ((tid >> 6) == 2) ? TANH_SC : SIG_SC;
    BS[L*256+tid] = sc * (L ? (bih1[tid]+bhh1[tid]) : (bih0[tid]+bhh0[tid]));
  } else if (b < 38){
    int idx = (b-36)*256 + tid;   // 0..383 used
    if (idx < 384){
      int lane = idx & 63, e = idx >> 6;   // e = ct*2+s, ct in 0..2
      int s = e & 1, ct = e >> 1;
      int kb = s*32 + (lane>>4)*8;
      int c = ct*16 + (lane&15);
      float w[8];
      #pragma unroll
      for (int j = 0; j < 8; ++j)
        w[j] = (c < 32) ? Wm1[(kb+j)*32 + c] : Wd1[(kb+j)*16 + (c-32)];
      uint4 v;
      v.x = bf16rne(w[0]) | (bf16rne(w[1])<<16);
      v.y = bf16rne(w[2]) | (bf16rne(w[3])<<16);
      v.z = bf16rne(w[4]) | (bf16rne(w[5])<<16);
      v.w = bf16rne(w[6]) | (bf16rne(w[7])<<16);
      WHF[idx] = v;
    }
  } else if (b < 234){
    int i = (b-38)*256 + tid;
    if (i < NN){ deg[i] = 1.0f; counts[i] = 0; }
  } else {
    int i = (b-234)*256 + tid;
    if (i < NN*49) xb[i] = (ushort)bf16rne(x[i]);
  }
}

// ---------------- graph norm / CSR build ----------------
__global__ void k_edge_count(const int* __restrict__ src, const int* __restrict__ dst,
                             const float* __restrict__ ew, float* deg, int* counts){
  int e = blockIdx.x*blockDim.x + threadIdx.x;
  if (e < EE){
    int d = dst[e];
    atomicAdd(&deg[d], ew[e]);
    atomicAdd(&counts[d], 1);
  }
}
__global__ __launch_bounds__(256) void k_scan_blk(const int* __restrict__ counts,
                                                  int* locincl, int* bsum, float* deg){
  int tid = threadIdx.x; int i = blockIdx.x*256 + tid;
  if (i < NN) deg[i] = rsqrtf(deg[i]);      // deg >= 1 always
  int v = (i < NN) ? counts[i] : 0;
  int lane = tid & 63;
  int val = v;
  #pragma unroll
  for (int off = 1; off < 64; off <<= 1){
    int u = __shfl_up(val, off, 64);
    if (lane >= off) val += u;
  }
  __shared__ int wsum[4];
  if (lane == 63) wsum[tid>>6] = val;
  __syncthreads();
  int w = tid >> 6, pre = 0;
  #pragma unroll
  for (int k = 0; k < 4; ++k) if (k < w) pre += wsum[k];
  int incl = val + pre;
  if (i < NN) locincl[i] = incl;
  if (tid == 255) bsum[blockIdx.x] = incl;
}
// fixup with the 196-wide top-scan inlined (every block redoes it; saves a dispatch)
__global__ __launch_bounds__(256) void k_scan_fix(const int* __restrict__ locincl,
        const int* __restrict__ bsum, const int* __restrict__ counts,
        int* rowptr, int* cursor){
  __shared__ int sb[256];
  __shared__ int wsum[4];
  int tid = threadIdx.x;
  int v = (tid < 196) ? bsum[tid] : 0;
  int lane = tid & 63;
  int val = v;
  #pragma unroll
  for (int off = 1; off < 64; off <<= 1){
    int u = __shfl_up(val, off, 64);
    if (lane >= off) val += u;
  }
  if (lane == 63) wsum[tid>>6] = val;
  __syncthreads();
  int w = tid >> 6, pre = 0;
  #pragma unroll
  for (int k = 0; k < 4; ++k) if (k < w) pre += wsum[k];
  sb[tid] = val + pre;     // inclusive scan of bsum
  __syncthreads();
  int boff = (blockIdx.x == 0) ? 0 : sb[blockIdx.x - 1];
  int i = blockIdx.x*256 + tid;
  if (i < NN){
    int r = locincl[i] + boff;
    rowptr[i+1] = r;
    cursor[i] = r - counts[i];
  }
  if (i == 0) rowptr[0] = 0;
}
__global__ void k_scatter(const int* __restrict__ src, const int* __restrict__ dst,
                          const float* __restrict__ ew, const float* __restrict__ dinv,
                          int* cursor, uint2* e2){
  int e = blockIdx.x*blockDim.x + threadIdx.x;
  if (e < EE){
    int s = src[e], d = dst[e];
    float nv = dinv[s]*ew[e]*dinv[d];
    int slot = atomicAdd(&cursor[d], 1);
    e2[slot] = make_uint2((uint)s, __float_as_uint(nv));
  }
}

// ---------------- GCN ----------------
// agg_x: 1 node per wave (full gather MLP — fusing this costs 4x, see R11/R12)
__global__ __launch_bounds__(256) void k_agg_x(const ushort* __restrict__ xb,
        const float* __restrict__ dinv, const int* __restrict__ rowptr,
        const uint2* __restrict__ e2, float* __restrict__ AX){
  int lane = threadIdx.x & 63, w = threadIdx.x >> 6;
  int i = blockIdx.x*4 + w;
  int beg = rowptr[i], end = rowptr[i+1];
  float di = dinv[i];
  float acc = 0.f;
  if (lane < 49) acc = di*di*bfu(xb[(size_t)i*49 + lane]);
  for (int s = beg; s < end; ++s){
    uint2 e = e2[s];
    int cs = (int)e.x; float wv = __uint_as_float(e.y);
    if (lane < 49) acc += wv * bfu(xb[(size_t)cs*49 + lane]);
  }
  if (lane < 49) AX[(size_t)i*49 + lane] = acc;
}
__global__ __launch_bounds__(256) void k_gcn2_mfma(const float* __restrict__ AX,
        const float* __restrict__ Wg1, const float* __restrict__ bg1,
        const uint4* __restrict__ WG2F, ushort* __restrict__ Z2p){
  __shared__ float sw1[448];
  __shared__ float sb1[64];
  __shared__ float sax[8*56];
  __shared__ __align__(16) ushort srb[64*68];
  int tid = threadIdx.x;
  int lane = tid & 63, w = tid >> 6;
  bf16x8 bw[4][2];
  #pragma unroll
  for (int ct = 0; ct < 4; ++ct)
    #pragma unroll
    for (int s = 0; s < 2; ++s){
      uint4 v = WG2F[(ct*2+s)*64 + lane];
      bw[ct][s] = *(bf16x8*)&v;
    }
  for (int i = tid; i < 448; i += 256) sw1[i] = Wg1[i];
  if (tid < 64) sb1[tid] = bg1[tid];
  int nbase = blockIdx.x*8;
  for (int i = tid; i < 448; i += 256){
    int n = i/56, c = i%56;
    sax[i] = (c < 49) ? AX[(size_t)(nbase+n)*49 + c] : 0.f;
  }
  __syncthreads();
  {
    int node = lane >> 3, t = lane & 7;
    float a[7];
    #pragma unroll
    for (int kk = 0; kk < 7; ++kk) a[kk] = sax[node*56 + t*7 + kk];
    ushort hv[16];
    #pragma unroll
    for (int j = 0; j < 16; ++j){
      int k = w*16 + j;
      float acc = sb1[k];
      #pragma unroll
      for (int kk = 0; kk < 7; ++kk) acc += a[kk]*sw1[kk*64+k];
      hv[j] = (ushort)bf16rne(leaky01(acc));
    }
    uint2* dst = (uint2*)&srb[lane*68 + w*16];
    #pragma unroll
    for (int q = 0; q < 4; ++q){
      uint2 v;
      v.x = (uint)hv[q*4+0] | ((uint)hv[q*4+1]<<16);
      v.y = (uint)hv[q*4+2] | ((uint)hv[q*4+3]<<16);
      dst[q] = v;
    }
  }
  __syncthreads();
  int col = lane & 15, quad = lane >> 4;
  bf16x8 afr[2];
  #pragma unroll
  for (int s = 0; s < 2; ++s){
    const ushort* pr = &srb[(w*16 + col)*68 + s*32 + quad*8];
    uint2 lo = *(const uint2*)pr;
    uint2 hi = *(const uint2*)(pr + 4);
    union { uint u[4]; bf16x8 b; } cv;
    cv.u[0]=lo.x; cv.u[1]=lo.y; cv.u[2]=hi.x; cv.u[3]=hi.y;
    afr[s] = cv.b;
  }
  f32x4 acc[4];
  #pragma unroll
  for (int ct = 0; ct < 4; ++ct) acc[ct] = (f32x4){0.f,0.f,0.f,0.f};
  #pragma unroll
  for (int ct = 0; ct < 4; ++ct)
    #pragma unroll
    for (int s = 0; s < 2; ++s)
      acc[ct] = __builtin_amdgcn_mfma_f32_16x16x32_bf16(afr[s], bw[ct][s], acc[ct], 0,0,0);
  int node = nbase + w*2 + (quad>>1);
  #pragma unroll
  for (int ct = 0; ct < 4; ++ct){
    uint2 v;
    v.x = bf16rne(acc[ct][0]) | (bf16rne(acc[ct][1])<<16);
    v.y = bf16rne(acc[ct][2]) | (bf16rne(acc[ct][3])<<16);
    size_t o = ((size_t)node*64 + ct*16 + col)*8 + (quad&1)*4;
    *(uint2*)(Z2p + o) = v;
  }
}
// Batched aggregation + LN over all 7 t. One wave per node; lane = feature.
__global__ __launch_bounds__(256) void k_agg_ln_all(const ushort* __restrict__ Z2p,
        const float* __restrict__ dinv, const int* __restrict__ rowptr,
        const uint2* __restrict__ e2,
        const float* __restrict__ bg2, const float* __restrict__ lng,
        const float* __restrict__ lnb, ushort* __restrict__ XT){
  int lane = threadIdx.x & 63, w = threadIdx.x >> 6;
  int i = blockIdx.x*4 + w;
  int beg = rowptr[i], end = rowptr[i+1];
  float di = dinv[i];
  float swt = di*di;
  const uint4* zp = (const uint4*)Z2p;
  float acc[7];
  {
    uint4 v = zp[(size_t)i*64 + lane];
    acc[0] = swt*bfu(v.x); acc[1] = swt*bfhi(v.x);
    acc[2] = swt*bfu(v.y); acc[3] = swt*bfhi(v.y);
    acc[4] = swt*bfu(v.z); acc[5] = swt*bfhi(v.z);
    acc[6] = swt*bfu(v.w);
  }
  for (int s = beg; s < end; ++s){
    uint2 e = e2[s];
    int cs = (int)e.x; float wv = __uint_as_float(e.y);
    uint4 v = zp[(size_t)cs*64 + lane];
    acc[0] = fmaf(wv, bfu(v.x),  acc[0]);
    acc[1] = fmaf(wv, bfhi(v.x), acc[1]);
    acc[2] = fmaf(wv, bfu(v.y),  acc[2]);
    acc[3] = fmaf(wv, bfhi(v.y), acc[3]);
    acc[4] = fmaf(wv, bfu(v.z),  acc[4]);
    acc[5] = fmaf(wv, bfhi(v.z), acc[5]);
    acc[6] = fmaf(wv, bfu(v.w),  acc[6]);
  }
  float b2 = bg2[lane], gl = lng[lane], bl = lnb[lane];
  #pragma unroll
  for (int t = 0; t < 7; ++t){
    float a = leaky01(acc[t] + b2);
    float sum = a;
    #pragma unroll
    for (int off = 32; off >= 1; off >>= 1) sum += __shfl_xor(sum, off, 64);
    float mu = sum * (1.f/64.f);
    float d = a - mu;
    float vs = d*d;
    #pragma unroll
    for (int off = 32; off >= 1; off >>= 1) vs += __shfl_xor(vs, off, 64);
    float rs = rsqrtf(vs*(1.f/64.f) + LN_EPS);
    XT[(size_t)t*NP*64 + (size_t)i*64 + lane] = (ushort)bf16rne(d*rs*gl + bl);
  }
}

// ---------------- LSTM (both layers, TRANSPOSED MFMA) + MFMA heads ----------------
// R10 structure (256 thr, 16 nodes/block, all waves active) + R11's verified
// transposed math: G^T = W·x^T. A = W frags, B = x^T/h^T frags (same packing &
// LDS reads as before). D[row=gate_local][col=node] -> each thread's 4 h outputs
// are contiguous units -> one ds_write_b64 (kills the 2M scalar-u16 conflicts).
__global__ __launch_bounds__(256) void k_lstm_heads(const ushort* __restrict__ xin,
        const uint4* __restrict__ WF, const float* __restrict__ BS,
        const uint4* __restrict__ WHF,
        const float* __restrict__ bm1, const float* __restrict__ bd1,
        const float* __restrict__ Wm2, const float* __restrict__ bm2,
        const float* __restrict__ Wd2, const float* __restrict__ bd2,
        float* __restrict__ out){
  __shared__ __align__(16) ushort XL[7][16][72];   // 15.75 KB
  int tid = threadIdx.x;
  int lane = tid & 63, cp = tid >> 6;
  int base = blockIdx.x*16;
  int col = lane & 15, quad = lane >> 4;
  bf16x8 hfr[2];
  for (int L = 0; L < 2; ++L){
    bf16x8 bwi[4][2], bwh[4][2];
    const uint4* wf = WF + L*4096;
    #pragma unroll
    for (int g = 0; g < 4; ++g){
      int ct = cp + 4*g;
      #pragma unroll
      for (int s = 0; s < 2; ++s){
        uint4 wi = wf[((ct*2+s)*2+0)*64 + lane];
        uint4 wh = wf[((ct*2+s)*2+1)*64 + lane];
        bwi[g][s] = *(bf16x8*)&wi;
        bwh[g][s] = *(bf16x8*)&wh;
      }
    }
    f32x4 bias4[4];
    #pragma unroll
    for (int g = 0; g < 4; ++g)
      bias4[g] = *(const f32x4*)&BS[L*256 + (cp + 4*g)*16 + quad*4];
    f32x4 cst = (f32x4){0.f,0.f,0.f,0.f};
    hfr[0] = (bf16x8){0,0,0,0,0,0,0,0};
    hfr[1] = (bf16x8){0,0,0,0,0,0,0,0};

    for (int t = 0; t < 7; ++t){
      bf16x8 ax[2];
      if (L == 0){
        #pragma unroll
        for (int s = 0; s < 2; ++s)
          ax[s] = *(const bf16x8*)(xin + (size_t)t*NP*64
                          + (size_t)(base + col)*64 + s*32 + quad*8);
      } else {
        #pragma unroll
        for (int s = 0; s < 2; ++s)
          ax[s] = *(const bf16x8*)&XL[t][col][s*32 + quad*8];
      }
      f32x4 acc[4];
      #pragma unroll
      for (int g = 0; g < 4; ++g) acc[g] = bias4[g];
      #pragma unroll
      for (int g = 0; g < 4; ++g){
        #pragma unroll
        for (int s = 0; s < 2; ++s){
          acc[g] = __builtin_amdgcn_mfma_f32_16x16x32_bf16(bwi[g][s], ax[s], acc[g], 0,0,0);
          acc[g] = __builtin_amdgcn_mfma_f32_16x16x32_bf16(bwh[g][s], hfr[s], acc[g], 0,0,0);
        }
      }
      if (L) __syncthreads();   // L1 only: all reads of plane t done before overwrite
      ushort hv[4];
      #pragma unroll
      for (int r = 0; r < 4; ++r){
        float ig = fastrcp(1.f + exp2fast(acc[0][r]));
        float fg = fastrcp(1.f + exp2fast(acc[1][r]));
        float gg = fmaf(-2.f, fastrcp(1.f + exp2fast(acc[2][r])), 1.f);
        float og = fastrcp(1.f + exp2fast(acc[3][r]));
        float cn = fmaf(fg, cst[r], ig*gg);
        cst[r] = cn;
        float tc = fmaf(-2.f, fastrcp(1.f + exp2fast(TANH_SC*cn)), 1.f);
        hv[r] = (ushort)bf16rne(og*tc);
      }
      // h for units 16cp+quad*4..+3, node col -> contiguous b64 write
      uint2 hw;
      hw.x = (uint)hv[0] | ((uint)hv[1]<<16);
      hw.y = (uint)hv[2] | ((uint)hv[3]<<16);
      *(uint2*)&XL[t][col][cp*16 + quad*4] = hw;
      __syncthreads();
      hfr[0] = *(const bf16x8*)&XL[t][col][quad*8];
      hfr[1] = *(const bf16x8*)&XL[t][col][32 + quad*8];
    }
  }
  // ---- heads: hfr = final h1 B-frags. First layer (64->48) via transposed MFMA. ----
  float* SH1 = (float*)&XL[0][0][0];   // planes 0-1 dead; [16][52] = 3.3 KB
  if (cp < 3){
    uint4 w0 = WHF[(cp*2+0)*64 + lane];
    uint4 w1 = WHF[(cp*2+1)*64 + lane];
    f32x4 hacc = (f32x4){0.f,0.f,0.f,0.f};
    hacc = __builtin_amdgcn_mfma_f32_16x16x32_bf16(*(bf16x8*)&w0, hfr[0], hacc, 0,0,0);
    hacc = __builtin_amdgcn_mfma_f32_16x16x32_bf16(*(bf16x8*)&w1, hfr[1], hacc, 0,0,0);
    float sv[4];
    #pragma unroll
    for (int r = 0; r < 4; ++r){
      int c = cp*16 + quad*4 + r;
      float b = (cp < 2) ? bm1[c] : bd1[c - 32];
      float v = hacc[r] + b;
      sv[r] = (cp < 2) ? leaky01(v) : fmaxf(v, 0.f);
    }
    *(float4*)&SH1[col*52 + cp*16 + quad*4] = make_float4(sv[0], sv[1], sv[2], sv[3]);
  }
  __syncthreads();
  // ---- second layer: 16 threads/node, shfl-reduce over the 16-lane group ----
  int node = tid >> 4, sub = tid & 15;
  int gn = base + node;
  float m1a = SH1[node*52 + sub];
  float m1b = SH1[node*52 + 16 + sub];
  float d1v = SH1[node*52 + 32 + sub];
  float4 wa = *(const float4*)&Wm2[sub*4];
  float4 wb = *(const float4*)&Wm2[(sub+16)*4];
  float4 wc = *(const float4*)&Wd2[sub*4];
  float pm0 = m1a*wa.x + m1b*wb.x, pm1 = m1a*wa.y + m1b*wb.y;
  float pm2 = m1a*wa.z + m1b*wb.z, pm3 = m1a*wa.w + m1b*wb.w;
  float pd0 = d1v*wc.x, pd1 = d1v*wc.y, pd2 = d1v*wc.z, pd3 = d1v*wc.w;
  #pragma unroll
  for (int off = 1; off < 16; off <<= 1){
    pm0 += __shfl_xor(pm0, off, 16); pm1 += __shfl_xor(pm1, off, 16);
    pm2 += __shfl_xor(pm2, off, 16); pm3 += __shfl_xor(pm3, off, 16);
    pd0 += __shfl_xor(pd0, off, 16); pd1 += __shfl_xor(pd1, off, 16);
    pd2 += __shfl_xor(pd2, off, 16); pd3 += __shfl_xor(pd3, off, 16);
  }
  if (sub < 4 && gn < NN){
    float mo = (sub==0)?pm0:(sub==1)?pm1:(sub==2)?pm2:pm3;
    float dv = (sub==0)?pd0:(sub==1)?pd1:(sub==2)?pd2:pd3;
    mo += bm2[sub]; dv += bd2[sub];
    out[(size_t)gn*4 + sub] = fmaxf(mo, 0.f) + 1e-4f;
    out[(size_t)NN*4 + (size_t)gn*4 + sub] = dv;
  }
}

extern "C" void kernel_launch(void* const* d_in, const int* in_sizes, int n_in,
                              void* d_out, int out_size, void* d_ws, size_t ws_size,
                              hipStream_t stream){
  const float* x    = (const float*)d_in[0];
  const int*   eidx = (const int*)d_in[1];
  const float* ew   = (const float*)d_in[2];
  const float* Wg1  = (const float*)d_in[3];
  const float* bg1  = (const float*)d_in[4];
  const float* Wg2  = (const float*)d_in[5];
  const float* bg2  = (const float*)d_in[6];
  const float* lng  = (const float*)d_in[7];
  const float* lnb  = (const float*)d_in[8];
  const float* Wih0 = (const float*)d_in[9];
  const float* Whh0 = (const float*)d_in[10];
  const float* bih0 = (const float*)d_in[11];
  const float* bhh0 = (const float*)d_in[12];
  const float* Wih1 = (const float*)d_in[13];
  const float* Whh1 = (const float*)d_in[14];
  const float* bih1 = (const float*)d_in[15];
  const float* bhh1 = (const float*)d_in[16];
  const float* Wm1  = (const float*)d_in[17];
  const float* bm1  = (const float*)d_in[18];
  const float* Wm2  = (const float*)d_in[19];
  const float* bm2  = (const float*)d_in[20];
  const float* Wd1  = (const float*)d_in[21];
  const float* bd1  = (const float*)d_in[22];
  const float* Wd2  = (const float*)d_in[23];
  const float* bd2  = (const float*)d_in[24];
  const int* src = eidx;
  const int* dst = eidx + EE;
  float* out = (float*)d_out;

  char* p = (char*)d_ws;
  auto alloc = [&](size_t bytes)->char*{ char* r = p; p += (bytes + 255) & ~(size_t)255; return r; };
  float*  deg     = (float*)alloc((size_t)NN*4);       // becomes dinv
  int*    counts  = (int*)  alloc((size_t)NN*4);
  int*    rowptr  = (int*)  alloc((size_t)(NN+1)*4);
  int*    cursor  = (int*)  alloc((size_t)NN*4);
  int*    locincl = (int*)  alloc((size_t)NN*4);
  int*    bsum    = (int*)  alloc((size_t)256*4);
  uint2*  e2      = (uint2*)alloc((size_t)EE*8);
  uint4*  WF      = (uint4*)alloc((size_t)2*4096*16);
  uint4*  WG2F    = (uint4*)alloc((size_t)512*16);
  uint4*  WHF     = (uint4*)alloc((size_t)384*16);
  float*  BS      = (float*)alloc((size_t)2*256*4);
  ushort* xb      = (ushort*)alloc((size_t)NN*49*2);
  ushort* XT      = (ushort*)alloc((size_t)TT*NP*64*2);
  float*  AX      = (float*)alloc((size_t)NN*49*4);
  ushort* Z2p     = (ushort*)alloc((size_t)NN*64*8*2);

  int xblocks = (NN*49 + 255)/256;                 // 9571
  k_prep_all<<<234 + xblocks, 256, 0, stream>>>(Wih0, Whh0, Wih1, Whh1, Wg2,
      bih0, bhh0, bih1, bhh1, Wm1, Wd1, x, WF, WG2F, WHF, BS, xb, deg, counts);
  k_edge_count<<<(EE+255)/256, 256, 0, stream>>>(src, dst, ew, deg, counts);
  k_scan_blk<<<196, 256, 0, stream>>>(counts, locincl, bsum, deg);
  k_scan_fix<<<196, 256, 0, stream>>>(locincl, bsum, counts, rowptr, cursor);
  k_scatter<<<(EE+255)/256, 256, 0, stream>>>(src, dst, ew, deg, cursor, e2);
  k_agg_x<<<NN/4, 256, 0, stream>>>(xb, deg, rowptr, e2, AX);
  k_gcn2_mfma<<<NN/8, 256, 0, stream>>>(AX, Wg1, bg1, WG2F, Z2p);
  k_agg_ln_all<<<NN/4, 256, 0, stream>>>(Z2p, deg, rowptr, e2, bg2, lng, lnb, XT);
  k_lstm_heads<<<NP/16, 256, 0, stream>>>(XT, WF, BS, WHF,
      bm1, bd1, Wm2, bm2, Wd2, bd2, out);
}

// Round 14
// 396.681 us; speedup vs baseline: 2.5173x; 1.0120x over previous
//
#include <hip/hip_runtime.h>
#include <stdint.h>

#define NN 50000
#define NP 50048          // padded to 64 for the MFMA LSTM kernel
#define EE 400000
#define TT 7
#define LN_EPS 1e-5f
#define SIG_SC (-1.4426950408889634f)   // -log2(e): sigmoid prescale
#define TANH_SC (2.8853900817779268f)   // +2*log2(e): tanh prescale

typedef __attribute__((ext_vector_type(8))) short bf16x8;
typedef __attribute__((ext_vector_type(4))) float f32x4;

__device__ __forceinline__ float leaky01(float x){ return x > 0.f ? x : 0.01f*x; }
__device__ __forceinline__ float fastrcp(float x){ return __builtin_amdgcn_rcpf(x); }
__device__ __forceinline__ float exp2fast(float x){ return __builtin_amdgcn_exp2f(x); }
__device__ __forceinline__ unsigned bf16rne(float f){
  unsigned u = __float_as_uint(f);
  return (u + 0x7fffu + ((u>>16)&1u)) >> 16;
}
__device__ __forceinline__ float bfu(unsigned u){ return __uint_as_float(u<<16); }
__device__ __forceinline__ float bfhi(unsigned u){ return __uint_as_float(u & 0xffff0000u); }

// ---------------- one-shot prep: weight packing + inits + x->bf16 ----------------
__global__ __launch_bounds__(256) void k_prep_all(
    const float* __restrict__ Wih0, const float* __restrict__ Whh0,
    const float* __restrict__ Wih1, const float* __restrict__ Whh1,
    const float* __restrict__ Wg2,
    const float* __restrict__ bih0, const float* __restrict__ bhh0,
    const float* __restrict__ bih1, const float* __restrict__ bhh1,
    const float* __restrict__ Wm1, const float* __restrict__ Wd1,
    const float* __restrict__ x,
    uint4* __restrict__ WF, uint4* __restrict__ WG2F, uint4* __restrict__ WHF,
    float* __restrict__ BS,
    ushort* __restrict__ xb, float* __restrict__ deg, int* __restrict__ counts){
  int b = blockIdx.x, tid = threadIdx.x;
  if (b < 32){
    int idx = b*256 + tid;
    int L = idx >> 12;
    int r = idx & 4095;
    int lane = r & 63;
    int e = r >> 6;
    int which = e & 1;
    int cs = e >> 1;
    int s = cs & 1, ct = cs >> 1;
    int row = ct*16 + (lane & 15);
    float sc = ((row >> 6) == 2) ? TANH_SC : SIG_SC;
    int kb = s*32 + (lane >> 4)*8;
    const float* W = L ? (which ? Whh1 : Wih1) : (which ? Whh0 : Wih0);
    const float* p = W + row*64 + kb;
    uint4 v;
    v.x = bf16rne(sc*p[0]) | (bf16rne(sc*p[1])<<16);
    v.y = bf16rne(sc*p[2]) | (bf16rne(sc*p[3])<<16);
    v.z = bf16rne(sc*p[4]) | (bf16rne(sc*p[5])<<16);
    v.w = bf16rne(sc*p[6]) | (bf16rne(sc*p[7])<<16);
    WF[idx] = v;
  } else if (b < 34){
    int idx = (b-32)*256 + tid;   // 0..511
    int lane = idx & 63, e = idx >> 6;   // e = ct*2+s
    int s = e & 1, ct = e >> 1;
    int kb = s*32 + (lane>>4)*8;
    int c = ct*16 + (lane&15);
    uint4 v;
    v.x = bf16rne(Wg2[(kb+0)*64+c]) | (bf16rne(Wg2[(kb+1)*64+c])<<16);
    v.y = bf16rne(Wg2[(kb+2)*64+c]) | (bf16rne(Wg2[(kb+3)*64+c])<<16);
    v.z = bf16rne(Wg2[(kb+4)*64+c]) | (bf16rne(Wg2[(kb+5)*64+c])<<16);
    v.w = bf16rne(Wg2[(kb+6)*64+c]) | (bf16rne(Wg2[(kb+7)*64+c])<<16);
    WG2F[idx] = v;
  } else if (b < 36){
    int L = b - 34;
    float sc = ((tid >> 6) == 2) ? TANH_SC : SIG_SC;
    BS[L*256+tid] = sc * (L ? (bih1[tid]+bhh1[tid]) : (bih0[tid]+bhh0[tid]));
  } else if (b < 38){
    int idx = (b-36)*256 + tid;   // 0..383 used
    if (idx < 384){
      int lane = idx & 63, e = idx >> 6;   // e = ct*2+s, ct in 0..2
      int s = e & 1, ct = e >> 1;
      int kb = s*32 + (lane>>4)*8;
      int c = ct*16 + (lane&15);
      float w[8];
      #pragma unroll
      for (int j = 0; j < 8; ++j)
        w[j] = (c < 32) ? Wm1[(kb+j)*32 + c] : Wd1[(kb+j)*16 + (c-32)];
      uint4 v;
      v.x = bf16rne(w[0]) | (bf16rne(w[1])<<16);
      v.y = bf16rne(w[2]) | (bf16rne(w[3])<<16);
      v.z = bf16rne(w[4]) | (bf16rne(w[5])<<16);
      v.w = bf16rne(w[6]) | (bf16rne(w[7])<<16);
      WHF[idx] = v;
    }
  } else if (b < 234){
    int i = (b-38)*256 + tid;
    if (i < NN){ deg[i] = 1.0f; counts[i] = 0; }
  } else {
    int i = (b-234)*256 + tid;
    if (i < NN*49) xb[i] = (ushort)bf16rne(x[i]);
  }
}

// ---------------- graph norm / CSR build ----------------
__global__ void k_edge_count(const int* __restrict__ src, const int* __restrict__ dst,
                             const float* __restrict__ ew, float* deg, int* counts){
  int e = blockIdx.x*blockDim.x + threadIdx.x;
  if (e < EE){
    int d = dst[e];
    atomicAdd(&deg[d], ew[e]);
    atomicAdd(&counts[d], 1);
  }
}
__global__ __launch_bounds__(256) void k_scan_blk(const int* __restrict__ counts,
                                                  int* locincl, int* bsum, float* deg){
  int tid = threadIdx.x; int i = blockIdx.x*256 + tid;
  if (i < NN) deg[i] = rsqrtf(deg[i]);      // deg >= 1 always
  int v = (i < NN) ? counts[i] : 0;
  int lane = tid & 63;
  int val = v;
  #pragma unroll
  for (int off = 1; off < 64; off <<= 1){
    int u = __shfl_up(val, off, 64);
    if (lane >= off) val += u;
  }
  __shared__ int wsum[4];
  if (lane == 63) wsum[tid>>6] = val;
  __syncthreads();
  int w = tid >> 6, pre = 0;
  #pragma unroll
  for (int k = 0; k < 4; ++k) if (k < w) pre += wsum[k];
  int incl = val + pre;
  if (i < NN) locincl[i] = incl;
  if (tid == 255) bsum[blockIdx.x] = incl;
}
// fixup with the 196-wide top-scan inlined (every block redoes it; saves a dispatch)
__global__ __launch_bounds__(256) void k_scan_fix(const int* __restrict__ locincl,
        const int* __restrict__ bsum, const int* __restrict__ counts,
        int* rowptr, int* cursor){
  __shared__ int sb[256];
  __shared__ int wsum[4];
  int tid = threadIdx.x;
  int v = (tid < 196) ? bsum[tid] : 0;
  int lane = tid & 63;
  int val = v;
  #pragma unroll
  for (int off = 1; off < 64; off <<= 1){
    int u = __shfl_up(val, off, 64);
    if (lane >= off) val += u;
  }
  if (lane == 63) wsum[tid>>6] = val;
  __syncthreads();
  int w = tid >> 6, pre = 0;
  #pragma unroll
  for (int k = 0; k < 4; ++k) if (k < w) pre += wsum[k];
  sb[tid] = val + pre;     // inclusive scan of bsum
  __syncthreads();
  int boff = (blockIdx.x == 0) ? 0 : sb[blockIdx.x - 1];
  int i = blockIdx.x*256 + tid;
  if (i < NN){
    int r = locincl[i] + boff;
    rowptr[i+1] = r;
    cursor[i] = r - counts[i];
  }
  if (i == 0) rowptr[0] = 0;
}
__global__ void k_scatter(const int* __restrict__ src, const int* __restrict__ dst,
                          const float* __restrict__ ew, const float* __restrict__ dinv,
                          int* cursor, uint2* e2){
  int e = blockIdx.x*blockDim.x + threadIdx.x;
  if (e < EE){
    int s = src[e], d = dst[e];
    float nv = dinv[s]*ew[e]*dinv[d];
    int slot = atomicAdd(&cursor[d], 1);
    e2[slot] = make_uint2((uint)s, __float_as_uint(nv));
  }
}

// ---------------- GCN ----------------
// agg_x: 1 node per wave (full gather MLP — fusing this costs 4x, see R11/R12)
__global__ __launch_bounds__(256) void k_agg_x(const ushort* __restrict__ xb,
        const float* __restrict__ dinv, const int* __restrict__ rowptr,
        const uint2* __restrict__ e2, float* __restrict__ AX){
  int lane = threadIdx.x & 63, w = threadIdx.x >> 6;
  int i = blockIdx.x*4 + w;
  int beg = rowptr[i], end = rowptr[i+1];
  float di = dinv[i];
  float acc = 0.f;
  if (lane < 49) acc = di*di*bfu(xb[(size_t)i*49 + lane]);
  for (int s = beg; s < end; ++s){
    uint2 e = e2[s];
    int cs = (int)e.x; float wv = __uint_as_float(e.y);
    if (lane < 49) acc += wv * bfu(xb[(size_t)cs*49 + lane]);
  }
  if (lane < 49) AX[(size_t)i*49 + lane] = acc;
}
__global__ __launch_bounds__(256) void k_gcn2_mfma(const float* __restrict__ AX,
        const float* __restrict__ Wg1, const float* __restrict__ bg1,
        const uint4* __restrict__ WG2F, ushort* __restrict__ Z2p){
  __shared__ float sw1[448];
  __shared__ float sb1[64];
  __shared__ float sax[8*56];
  __shared__ __align__(16) ushort srb[64*68];
  int tid = threadIdx.x;
  int lane = tid & 63, w = tid >> 6;
  bf16x8 bw[4][2];
  #pragma unroll
  for (int ct = 0; ct < 4; ++ct)
    #pragma unroll
    for (int s = 0; s < 2; ++s){
      uint4 v = WG2F[(ct*2+s)*64 + lane];
      bw[ct][s] = *(bf16x8*)&v;
    }
  for (int i = tid; i < 448; i += 256) sw1[i] = Wg1[i];
  if (tid < 64) sb1[tid] = bg1[tid];
  int nbase = blockIdx.x*8;
  for (int i = tid; i < 448; i += 256){
    int n = i/56, c = i%56;
    sax[i] = (c < 49) ? AX[(size_t)(nbase+n)*49 + c] : 0.f;
  }
  __syncthreads();
  {
    int node = lane >> 3, t = lane & 7;
    float a[7];
    #pragma unroll
    for (int kk = 0; kk < 7; ++kk) a[kk] = sax[node*56 + t*7 + kk];
    ushort hv[16];
    #pragma unroll
    for (int j = 0; j < 16; ++j){
      int k = w*16 + j;
      float acc = sb1[k];
      #pragma unroll
      for (int kk = 0; kk < 7; ++kk) acc += a[kk]*sw1[kk*64+k];
      hv[j] = (ushort)bf16rne(leaky01(acc));
    }
    uint2* dst = (uint2*)&srb[lane*68 + w*16];
    #pragma unroll
    for (int q = 0; q < 4; ++q){
      uint2 v;
      v.x = (uint)hv[q*4+0] | ((uint)hv[q*4+1]<<16);
      v.y = (uint)hv[q*4+2] | ((uint)hv[q*4+3]<<16);
      dst[q] = v;
    }
  }
  __syncthreads();
  int col = lane & 15, quad = lane >> 4;
  bf16x8 afr[2];
  #pragma unroll
  for (int s = 0; s < 2; ++s){
    const ushort* pr = &srb[(w*16 + col)*68 + s*32 + quad*8];
    uint2 lo = *(const uint2*)pr;
    uint2 hi = *(const uint2*)(pr + 4);
    union { uint u[4]; bf16x8 b; } cv;
    cv.u[0]=lo.x; cv.u[1]=lo.y; cv.u[2]=hi.x; cv.u[3]=hi.y;
    afr[s] = cv.b;
  }
  f32x4 acc[4];
  #pragma unroll
  for (int ct = 0; ct < 4; ++ct) acc[ct] = (f32x4){0.f,0.f,0.f,0.f};
  #pragma unroll
  for (int ct = 0; ct < 4; ++ct)
    #pragma unroll
    for (int s = 0; s < 2; ++s)
      acc[ct] = __builtin_amdgcn_mfma_f32_16x16x32_bf16(afr[s], bw[ct][s], acc[ct], 0,0,0);
  int node = nbase + w*2 + (quad>>1);
  #pragma unroll
  for (int ct = 0; ct < 4; ++ct){
    uint2 v;
    v.x = bf16rne(acc[ct][0]) | (bf16rne(acc[ct][1])<<16);
    v.y = bf16rne(acc[ct][2]) | (bf16rne(acc[ct][3])<<16);
    size_t o = ((size_t)node*64 + ct*16 + col)*8 + (quad&1)*4;
    *(uint2*)(Z2p + o) = v;
  }
}
// Batched aggregation + LN over all 7 t. One wave per node; lane = feature.
__global__ __launch_bounds__(256) void k_agg_ln_all(const ushort* __restrict__ Z2p,
        const float* __restrict__ dinv, const int* __restrict__ rowptr,
        const uint2* __restrict__ e2,
        const float* __restrict__ bg2, const float* __restrict__ lng,
        const float* __restrict__ lnb, ushort* __restrict__ XT){
  int lane = threadIdx.x & 63, w = threadIdx.x >> 6;
  int i = blockIdx.x*4 + w;
  int beg = rowptr[i], end = rowptr[i+1];
  float di = dinv[i];
  float swt = di*di;
  const uint4* zp = (const uint4*)Z2p;
  float acc[7];
  {
    uint4 v = zp[(size_t)i*64 + lane];
    acc[0] = swt*bfu(v.x); acc[1] = swt*bfhi(v.x);
    acc[2] = swt*bfu(v.y); acc[3] = swt*bfhi(v.y);
    acc[4] = swt*bfu(v.z); acc[5] = swt*bfhi(v.z);
    acc[6] = swt*bfu(v.w);
  }
  for (int s = beg; s < end; ++s){
    uint2 e = e2[s];
    int cs = (int)e.x; float wv = __uint_as_float(e.y);
    uint4 v = zp[(size_t)cs*64 + lane];
    acc[0] = fmaf(wv, bfu(v.x),  acc[0]);
    acc[1] = fmaf(wv, bfhi(v.x), acc[1]);
    acc[2] = fmaf(wv, bfu(v.y),  acc[2]);
    acc[3] = fmaf(wv, bfhi(v.y), acc[3]);
    acc[4] = fmaf(wv, bfu(v.z),  acc[4]);
    acc[5] = fmaf(wv, bfhi(v.z), acc[5]);
    acc[6] = fmaf(wv, bfu(v.w),  acc[6]);
  }
  float b2 = bg2[lane], gl = lng[lane], bl = lnb[lane];
  #pragma unroll
  for (int t = 0; t < 7; ++t){
    float a = leaky01(acc[t] + b2);
    float sum = a;
    #pragma unroll
    for (int off = 32; off >= 1; off >>= 1) sum += __shfl_xor(sum, off, 64);
    float mu = sum * (1.f/64.f);
    float d = a - mu;
    float vs = d*d;
    #pragma unroll
    for (int off = 32; off >= 1; off >>= 1) vs += __shfl_xor(vs, off, 64);
    float rs = rsqrtf(vs*(1.f/64.f) + LN_EPS);
    XT[(size_t)t*NP*64 + (size_t)i*64 + lane] = (ushort)bf16rne(d*rs*gl + bl);
  }
}

// ---------------- LSTM (both layers) + MFMA heads — R10 body + HB ping-pong ----------------
// 16 nodes/block, 4 waves split gate-column tiles (R10-proven, non-transposed).
// L0: h0[t] written to plane XL[t] (L1's input) — 1 barrier/t.
// L1: planes are READ-ONLY; h1 exchanged via ping-pong HB[t&1] — 1 barrier/t
//     (was 2: the pre-epilogue WAR barrier is gone). WAR on HB[p] is separated
//     by barrier_{t+1} between the t-read and the (t+2)-write.
__global__ __launch_bounds__(256) void k_lstm_heads(const ushort* __restrict__ xin,
        const uint4* __restrict__ WF, const float* __restrict__ BS,
        const uint4* __restrict__ WHF,
        const float* __restrict__ bm1, const float* __restrict__ bd1,
        const float* __restrict__ Wm2, const float* __restrict__ bm2,
        const float* __restrict__ Wd2, const float* __restrict__ bd2,
        float* __restrict__ out){
  __shared__ __align__(16) ushort XL[7][16][72];   // 15.75 KB (h0 planes)
  __shared__ __align__(16) ushort HB[2][16][72];   // 4.5 KB (L1 h ping-pong)
  int tid = threadIdx.x;
  int lane = tid & 63, cp = tid >> 6;
  int base = blockIdx.x*16;
  int col = lane & 15, quad = lane >> 4;
  bf16x8 hfr[2];
  for (int L = 0; L < 2; ++L){
    bf16x8 bwi[4][2], bwh[4][2];
    const uint4* wf = WF + L*4096;
    #pragma unroll
    for (int g = 0; g < 4; ++g){
      int ct = cp + 4*g;
      #pragma unroll
      for (int s = 0; s < 2; ++s){
        uint4 wi = wf[((ct*2+s)*2+0)*64 + lane];
        uint4 wh = wf[((ct*2+s)*2+1)*64 + lane];
        bwi[g][s] = *(bf16x8*)&wi;
        bwh[g][s] = *(bf16x8*)&wh;
      }
    }
    float bias[4];
    #pragma unroll
    for (int g = 0; g < 4; ++g) bias[g] = BS[L*256 + (cp + 4*g)*16 + col];
    f32x4 cst = (f32x4){0.f,0.f,0.f,0.f};
    hfr[0] = (bf16x8){0,0,0,0,0,0,0,0};
    hfr[1] = (bf16x8){0,0,0,0,0,0,0,0};

    for (int t = 0; t < 7; ++t){
      bf16x8 ax[2];
      if (L == 0){
        #pragma unroll
        for (int s = 0; s < 2; ++s)
          ax[s] = *(const bf16x8*)(xin + (size_t)t*NP*64
                          + (size_t)(base + col)*64 + s*32 + quad*8);
      } else {
        #pragma unroll
        for (int s = 0; s < 2; ++s)
          ax[s] = *(const bf16x8*)&XL[t][col][s*32 + quad*8];
      }
      f32x4 acc[4];
      #pragma unroll
      for (int g = 0; g < 4; ++g){
        float b = bias[g];
        acc[g] = (f32x4){b,b,b,b};
      }
      #pragma unroll
      for (int g = 0; g < 4; ++g){
        #pragma unroll
        for (int s = 0; s < 2; ++s){
          acc[g] = __builtin_amdgcn_mfma_f32_16x16x32_bf16(ax[s], bwi[g][s], acc[g], 0,0,0);
          acc[g] = __builtin_amdgcn_mfma_f32_16x16x32_bf16(hfr[s], bwh[g][s], acc[g], 0,0,0);
        }
      }
      ushort (*dstp)[72] = (L == 0) ? XL[t] : HB[t & 1];
      #pragma unroll
      for (int r = 0; r < 4; ++r){
        float ig = fastrcp(1.f + exp2fast(acc[0][r]));
        float fg = fastrcp(1.f + exp2fast(acc[1][r]));
        float gg = fmaf(-2.f, fastrcp(1.f + exp2fast(acc[2][r])), 1.f);
        float og = fastrcp(1.f + exp2fast(acc[3][r]));
        float cn = fmaf(fg, cst[r], ig*gg);
        cst[r] = cn;
        float tc = fmaf(-2.f, fastrcp(1.f + exp2fast(TANH_SC*cn)), 1.f);
        dstp[quad*4 + r][cp*16 + col] = (ushort)bf16rne(og*tc);
      }
      __syncthreads();
      hfr[0] = *(const bf16x8*)&dstp[col][quad*8];
      hfr[1] = *(const bf16x8*)&dstp[col][32 + quad*8];
    }
  }
  // ---- heads: hfr = final h1 A-frags. First layer (64->48) via MFMA (R10). ----
  float* SH1 = (float*)&XL[0][0][0];   // planes 0-1 dead; [16][52] = 3.3 KB
  if (cp < 3){
    uint4 w0 = WHF[(cp*2+0)*64 + lane];
    uint4 w1 = WHF[(cp*2+1)*64 + lane];
    f32x4 hacc = (f32x4){0.f,0.f,0.f,0.f};
    hacc = __builtin_amdgcn_mfma_f32_16x16x32_bf16(hfr[0], *(bf16x8*)&w0, hacc, 0,0,0);
    hacc = __builtin_amdgcn_mfma_f32_16x16x32_bf16(hfr[1], *(bf16x8*)&w1, hacc, 0,0,0);
    #pragma unroll
    for (int r = 0; r < 4; ++r){
      int c = cp*16 + col;
      float b = (cp < 2) ? bm1[c] : bd1[col];
      float v = hacc[r] + b;
      v = (cp < 2) ? leaky01(v) : fmaxf(v, 0.f);
      SH1[(quad*4 + r)*52 + cp*16 + col] = v;
    }
  }
  __syncthreads();
  // ---- second layer: 16 threads/node, shfl-reduce over the 16-lane group ----
  int node = tid >> 4, sub = tid & 15;
  int gn = base + node;
  float m1a = SH1[node*52 + sub];
  float m1b = SH1[node*52 + 16 + sub];
  float d1v = SH1[node*52 + 32 + sub];
  float4 wa = *(const float4*)&Wm2[sub*4];
  float4 wb = *(const float4*)&Wm2[(sub+16)*4];
  float4 wc = *(const float4*)&Wd2[sub*4];
  float pm0 = m1a*wa.x + m1b*wb.x, pm1 = m1a*wa.y + m1b*wb.y;
  float pm2 = m1a*wa.z + m1b*wb.z, pm3 = m1a*wa.w + m1b*wb.w;
  float pd0 = d1v*wc.x, pd1 = d1v*wc.y, pd2 = d1v*wc.z, pd3 = d1v*wc.w;
  #pragma unroll
  for (int off = 1; off < 16; off <<= 1){
    pm0 += __shfl_xor(pm0, off, 16); pm1 += __shfl_xor(pm1, off, 16);
    pm2 += __shfl_xor(pm2, off, 16); pm3 += __shfl_xor(pm3, off, 16);
    pd0 += __shfl_xor(pd0, off, 16); pd1 += __shfl_xor(pd1, off, 16);
    pd2 += __shfl_xor(pd2, off, 16); pd3 += __shfl_xor(pd3, off, 16);
  }
  if (sub < 4 && gn < NN){
    float mo = (sub==0)?pm0:(sub==1)?pm1:(sub==2)?pm2:pm3;
    float dv = (sub==0)?pd0:(sub==1)?pd1:(sub==2)?pd2:pd3;
    mo += bm2[sub]; dv += bd2[sub];
    out[(size_t)gn*4 + sub] = fmaxf(mo, 0.f) + 1e-4f;
    out[(size_t)NN*4 + (size_t)gn*4 + sub] = dv;
  }
}

extern "C" void kernel_launch(void* const* d_in, const int* in_sizes, int n_in,
                              void* d_out, int out_size, void* d_ws, size_t ws_size,
                              hipStream_t stream){
  const float* x    = (const float*)d_in[0];
  const int*   eidx = (const int*)d_in[1];
  const float* ew   = (const float*)d_in[2];
  const float* Wg1  = (const float*)d_in[3];
  const float* bg1  = (const float*)d_in[4];
  const float* Wg2  = (const float*)d_in[5];
  const float* bg2  = (const float*)d_in[6];
  const float* lng  = (const float*)d_in[7];
  const float* lnb  = (const float*)d_in[8];
  const float* Wih0 = (const float*)d_in[9];
  const float* Whh0 = (const float*)d_in[10];
  const float* bih0 = (const float*)d_in[11];
  const float* bhh0 = (const float*)d_in[12];
  const float* Wih1 = (const float*)d_in[13];
  const float* Whh1 = (const float*)d_in[14];
  const float* bih1 = (const float*)d_in[15];
  const float* bhh1 = (const float*)d_in[16];
  const float* Wm1  = (const float*)d_in[17];
  const float* bm1  = (const float*)d_in[18];
  const float* Wm2  = (const float*)d_in[19];
  const float* bm2  = (const float*)d_in[20];
  const float* Wd1  = (const float*)d_in[21];
  const float* bd1  = (const float*)d_in[22];
  const float* Wd2  = (const float*)d_in[23];
  const float* bd2  = (const float*)d_in[24];
  const int* src = eidx;
  const int* dst = eidx + EE;
  float* out = (float*)d_out;

  char* p = (char*)d_ws;
  auto alloc = [&](size_t bytes)->char*{ char* r = p; p += (bytes + 255) & ~(size_t)255; return r; };
  float*  deg     = (float*)alloc((size_t)NN*4);       // becomes dinv
  int*    counts  = (int*)  alloc((size_t)NN*4);
  int*    rowptr  = (int*)  alloc((size_t)(NN+1)*4);
  int*    cursor  = (int*)  alloc((size_t)NN*4);
  int*    locincl = (int*)  alloc((size_t)NN*4);
  int*    bsum    = (int*)  alloc((size_t)256*4);
  uint2*  e2      = (uint2*)alloc((size_t)EE*8);
  uint4*  WF      = (uint4*)alloc((size_t)2*4096*16);
  uint4*  WG2F    = (uint4*)alloc((size_t)512*16);
  uint4*  WHF     = (uint4*)alloc((size_t)384*16);
  float*  BS      = (float*)alloc((size_t)2*256*4);
  ushort* xb      = (ushort*)alloc((size_t)NN*49*2);
  ushort* XT      = (ushort*)alloc((size_t)TT*NP*64*2);
  float*  AX      = (float*)alloc((size_t)NN*49*4);
  ushort* Z2p     = (ushort*)alloc((size_t)NN*64*8*2);

  int xblocks = (NN*49 + 255)/256;                 // 9571
  k_prep_all<<<234 + xblocks, 256, 0, stream>>>(Wih0, Whh0, Wih1, Whh1, Wg2,
      bih0, bhh0, bih1, bhh1, Wm1, Wd1, x, WF, WG2F, WHF, BS, xb, deg, counts);
  k_edge_count<<<(EE+255)/256, 256, 0, stream>>>(src, dst, ew, deg, counts);
  k_scan_blk<<<196, 256, 0, stream>>>(counts, locincl, bsum, deg);
  k_scan_fix<<<196, 256, 0, stream>>>(locincl, bsum, counts, rowptr, cursor);
  k_scatter<<<(EE+255)/256, 256, 0, stream>>>(src, dst, ew, deg, cursor, e2);
  k_agg_x<<<NN/4, 256, 0, stream>>>(xb, deg, rowptr, e2, AX);
  k_gcn2_mfma<<<NN/8, 256, 0, stream>>>(AX, Wg1, bg1, WG2F, Z2p);
  k_agg_ln_all<<<NN/4, 256, 0, stream>>>(Z2p, deg, rowptr, e2, bg2, lng, lnb, XT);
  k_lstm_heads<<<NP/16, 256, 0, stream>>>(XT, WF, BS, WHF,
      bm1, bd1, Wm2, bm2, Wd2, bd2, out);
}

// Round 15
// 373.011 us; speedup vs baseline: 2.6771x; 1.0635x over previous
//
#include <hip/hip_runtime.h>
#include <stdint.h>

#define NN 50000
#define NP 50048          // padded to 64 for the MFMA LSTM kernel
#define EE 400000
#define TT 7
#define LN_EPS 1e-5f
#define SIG_SC (-1.4426950408889634f)   // -log2(e): sigmoid prescale
#define TANH_SC (2.8853900817779268f)   // +2*log2(e): tanh prescale

typedef __attribute__((ext_vector_type(8))) short bf16x8;
typedef __attribute__((ext_vector_type(4))) float f32x4;

__device__ __forceinline__ float leaky01(float x){ return x > 0.f ? x : 0.01f*x; }
__device__ __forceinline__ float fastrcp(float x){ return __builtin_amdgcn_rcpf(x); }
__device__ __forceinline__ float exp2fast(float x){ return __builtin_amdgcn_exp2f(x); }
__device__ __forceinline__ unsigned bf16rne(float f){
  unsigned u = __float_as_uint(f);
  return (u + 0x7fffu + ((u>>16)&1u)) >> 16;
}
__device__ __forceinline__ float bfu(unsigned u){ return __uint_as_float(u<<16); }
__device__ __forceinline__ float bfhi(unsigned u){ return __uint_as_float(u & 0xffff0000u); }

// ---------------- one-shot prep: weight packing + inits + x->bf16 ----------------
__global__ __launch_bounds__(256) void k_prep_all(
    const float* __restrict__ Wih0, const float* __restrict__ Whh0,
    const float* __restrict__ Wih1, const float* __restrict__ Whh1,
    const float* __restrict__ Wg2,
    const float* __restrict__ bih0, const float* __restrict__ bhh0,
    const float* __restrict__ bih1, const float* __restrict__ bhh1,
    const float* __restrict__ Wm1, const float* __restrict__ Wd1,
    const float* __restrict__ x,
    uint4* __restrict__ WF, uint4* __restrict__ WG2F, uint4* __restrict__ WHF,
    float* __restrict__ BS,
    ushort* __restrict__ xb, float* __restrict__ deg, int* __restrict__ counts){
  int b = blockIdx.x, tid = threadIdx.x;
  if (b < 32){
    int idx = b*256 + tid;
    int L = idx >> 12;
    int r = idx & 4095;
    int lane = r & 63;
    int e = r >> 6;
    int which = e & 1;
    int cs = e >> 1;
    int s = cs & 1, ct = cs >> 1;
    int row = ct*16 + (lane & 15);
    float sc = ((row >> 6) == 2) ? TANH_SC : SIG_SC;
    int kb = s*32 + (lane >> 4)*8;
    const float* W = L ? (which ? Whh1 : Wih1) : (which ? Whh0 : Wih0);
    const float* p = W + row*64 + kb;
    uint4 v;
    v.x = bf16rne(sc*p[0]) | (bf16rne(sc*p[1])<<16);
    v.y = bf16rne(sc*p[2]) | (bf16rne(sc*p[3])<<16);
    v.z = bf16rne(sc*p[4]) | (bf16rne(sc*p[5])<<16);
    v.w = bf16rne(sc*p[6]) | (bf16rne(sc*p[7])<<16);
    WF[idx] = v;
  } else if (b < 34){
    int idx = (b-32)*256 + tid;   // 0..511
    int lane = idx & 63, e = idx >> 6;   // e = ct*2+s
    int s = e & 1, ct = e >> 1;
    int kb = s*32 + (lane>>4)*8;
    int c = ct*16 + (lane&15);
    uint4 v;
    v.x = bf16rne(Wg2[(kb+0)*64+c]) | (bf16rne(Wg2[(kb+1)*64+c])<<16);
    v.y = bf16rne(Wg2[(kb+2)*64+c]) | (bf16rne(Wg2[(kb+3)*64+c])<<16);
    v.z = bf16rne(Wg2[(kb+4)*64+c]) | (bf16rne(Wg2[(kb+5)*64+c])<<16);
    v.w = bf16rne(Wg2[(kb+6)*64+c]) | (bf16rne(Wg2[(kb+7)*64+c])<<16);
    WG2F[idx] = v;
  } else if (b < 36){
    int L = b - 34;
    float sc = ((tid >> 6) == 2) ? TANH_SC : SIG_SC;
    BS[L*256+tid] = sc * (L ? (bih1[tid]+bhh1[tid]) : (bih0[tid]+bhh0[tid]));
  } else if (b < 38){
    int idx = (b-36)*256 + tid;   // 0..383 used
    if (idx < 384){
      int lane = idx & 63, e = idx >> 6;   // e = ct*2+s, ct in 0..2
      int s = e & 1, ct = e >> 1;
      int kb = s*32 + (lane>>4)*8;
      int c = ct*16 + (lane&15);
      float w[8];
      #pragma unroll
      for (int j = 0; j < 8; ++j)
        w[j] = (c < 32) ? Wm1[(kb+j)*32 + c] : Wd1[(kb+j)*16 + (c-32)];
      uint4 v;
      v.x = bf16rne(w[0]) | (bf16rne(w[1])<<16);
      v.y = bf16rne(w[2]) | (bf16rne(w[3])<<16);
      v.z = bf16rne(w[4]) | (bf16rne(w[5])<<16);
      v.w = bf16rne(w[6]) | (bf16rne(w[7])<<16);
      WHF[idx] = v;
    }
  } else if (b < 234){
    int i = (b-38)*256 + tid;
    if (i < NN){ deg[i] = 1.0f; counts[i] = 0; }
  } else {
    int i = (b-234)*256 + tid;
    if (i < NN*49) xb[i] = (ushort)bf16rne(x[i]);
  }
}

// ---------------- graph norm / CSR build ----------------
__global__ void k_edge_count(const int* __restrict__ src, const int* __restrict__ dst,
                             const float* __restrict__ ew, float* deg, int* counts){
  int e = blockIdx.x*blockDim.x + threadIdx.x;
  if (e < EE){
    int d = dst[e];
    atomicAdd(&deg[d], ew[e]);
    atomicAdd(&counts[d], 1);
  }
}
__global__ __launch_bounds__(256) void k_scan_blk(const int* __restrict__ counts,
                                                  int* locincl, int* bsum, float* deg){
  int tid = threadIdx.x; int i = blockIdx.x*256 + tid;
  if (i < NN) deg[i] = rsqrtf(deg[i]);      // deg >= 1 always
  int v = (i < NN) ? counts[i] : 0;
  int lane = tid & 63;
  int val = v;
  #pragma unroll
  for (int off = 1; off < 64; off <<= 1){
    int u = __shfl_up(val, off, 64);
    if (lane >= off) val += u;
  }
  __shared__ int wsum[4];
  if (lane == 63) wsum[tid>>6] = val;
  __syncthreads();
  int w = tid >> 6, pre = 0;
  #pragma unroll
  for (int k = 0; k < 4; ++k) if (k < w) pre += wsum[k];
  int incl = val + pre;
  if (i < NN) locincl[i] = incl;
  if (tid == 255) bsum[blockIdx.x] = incl;
}
// fixup with the 196-wide top-scan inlined (every block redoes it; saves a dispatch)
__global__ __launch_bounds__(256) void k_scan_fix(const int* __restrict__ locincl,
        const int* __restrict__ bsum, const int* __restrict__ counts,
        int* rowptr, int* cursor){
  __shared__ int sb[256];
  __shared__ int wsum[4];
  int tid = threadIdx.x;
  int v = (tid < 196) ? bsum[tid] : 0;
  int lane = tid & 63;
  int val = v;
  #pragma unroll
  for (int off = 1; off < 64; off <<= 1){
    int u = __shfl_up(val, off, 64);
    if (lane >= off) val += u;
  }
  if (lane == 63) wsum[tid>>6] = val;
  __syncthreads();
  int w = tid >> 6, pre = 0;
  #pragma unroll
  for (int k = 0; k < 4; ++k) if (k < w) pre += wsum[k];
  sb[tid] = val + pre;     // inclusive scan of bsum
  __syncthreads();
  int boff = (blockIdx.x == 0) ? 0 : sb[blockIdx.x - 1];
  int i = blockIdx.x*256 + tid;
  if (i < NN){
    int r = locincl[i] + boff;
    rowptr[i+1] = r;
    cursor[i] = r - counts[i];
  }
  if (i == 0) rowptr[0] = 0;
}
__global__ void k_scatter(const int* __restrict__ src, const int* __restrict__ dst,
                          const float* __restrict__ ew, const float* __restrict__ dinv,
                          int* cursor, uint2* e2){
  int e = blockIdx.x*blockDim.x + threadIdx.x;
  if (e < EE){
    int s = src[e], d = dst[e];
    float nv = dinv[s]*ew[e]*dinv[d];
    int slot = atomicAdd(&cursor[d], 1);
    e2[slot] = make_uint2((uint)s, __float_as_uint(nv));
  }
}

// ---------------- GCN ----------------
// agg_x: 1 node/wave, edge loop unrolled 4x for memory-level parallelism
__global__ __launch_bounds__(256) void k_agg_x(const ushort* __restrict__ xb,
        const float* __restrict__ dinv, const int* __restrict__ rowptr,
        const uint2* __restrict__ e2, float* __restrict__ AX){
  int lane = threadIdx.x & 63, w = threadIdx.x >> 6;
  int i = blockIdx.x*4 + w;
  int beg = rowptr[i], end = rowptr[i+1];
  float di = dinv[i];
  float acc = 0.f;
  if (lane < 49) acc = di*di*bfu(xb[(size_t)i*49 + lane]);
  int s = beg;
  for (; s + 4 <= end; s += 4){
    uint2 ea = e2[s],   eb = e2[s+1];
    uint2 ec = e2[s+2], ed = e2[s+3];
    float va = 0.f, vb = 0.f, vc = 0.f, vd = 0.f;
    if (lane < 49){
      va = bfu(xb[(size_t)ea.x*49 + lane]);
      vb = bfu(xb[(size_t)eb.x*49 + lane]);
      vc = bfu(xb[(size_t)ec.x*49 + lane]);
      vd = bfu(xb[(size_t)ed.x*49 + lane]);
    }
    acc = fmaf(__uint_as_float(ea.y), va, acc);
    acc = fmaf(__uint_as_float(eb.y), vb, acc);
    acc = fmaf(__uint_as_float(ec.y), vc, acc);
    acc = fmaf(__uint_as_float(ed.y), vd, acc);
  }
  for (; s < end; ++s){
    uint2 e = e2[s];
    if (lane < 49) acc = fmaf(__uint_as_float(e.y), bfu(xb[(size_t)e.x*49 + lane]), acc);
  }
  if (lane < 49) AX[(size_t)i*49 + lane] = acc;
}
__global__ __launch_bounds__(256) void k_gcn2_mfma(const float* __restrict__ AX,
        const float* __restrict__ Wg1, const float* __restrict__ bg1,
        const uint4* __restrict__ WG2F, ushort* __restrict__ Z2p){
  __shared__ float sw1[448];
  __shared__ float sb1[64];
  __shared__ float sax[8*56];
  __shared__ __align__(16) ushort srb[64*68];
  int tid = threadIdx.x;
  int lane = tid & 63, w = tid >> 6;
  bf16x8 bw[4][2];
  #pragma unroll
  for (int ct = 0; ct < 4; ++ct)
    #pragma unroll
    for (int s = 0; s < 2; ++s){
      uint4 v = WG2F[(ct*2+s)*64 + lane];
      bw[ct][s] = *(bf16x8*)&v;
    }
  for (int i = tid; i < 448; i += 256) sw1[i] = Wg1[i];
  if (tid < 64) sb1[tid] = bg1[tid];
  int nbase = blockIdx.x*8;
  for (int i = tid; i < 448; i += 256){
    int n = i/56, c = i%56;
    sax[i] = (c < 49) ? AX[(size_t)(nbase+n)*49 + c] : 0.f;
  }
  __syncthreads();
  {
    int node = lane >> 3, t = lane & 7;
    float a[7];
    #pragma unroll
    for (int kk = 0; kk < 7; ++kk) a[kk] = sax[node*56 + t*7 + kk];
    ushort hv[16];
    #pragma unroll
    for (int j = 0; j < 16; ++j){
      int k = w*16 + j;
      float acc = sb1[k];
      #pragma unroll
      for (int kk = 0; kk < 7; ++kk) acc += a[kk]*sw1[kk*64+k];
      hv[j] = (ushort)bf16rne(leaky01(acc));
    }
    uint2* dst = (uint2*)&srb[lane*68 + w*16];
    #pragma unroll
    for (int q = 0; q < 4; ++q){
      uint2 v;
      v.x = (uint)hv[q*4+0] | ((uint)hv[q*4+1]<<16);
      v.y = (uint)hv[q*4+2] | ((uint)hv[q*4+3]<<16);
      dst[q] = v;
    }
  }
  __syncthreads();
  int col = lane & 15, quad = lane >> 4;
  bf16x8 afr[2];
  #pragma unroll
  for (int s = 0; s < 2; ++s){
    const ushort* pr = &srb[(w*16 + col)*68 + s*32 + quad*8];
    uint2 lo = *(const uint2*)pr;
    uint2 hi = *(const uint2*)(pr + 4);
    union { uint u[4]; bf16x8 b; } cv;
    cv.u[0]=lo.x; cv.u[1]=lo.y; cv.u[2]=hi.x; cv.u[3]=hi.y;
    afr[s] = cv.b;
  }
  f32x4 acc[4];
  #pragma unroll
  for (int ct = 0; ct < 4; ++ct) acc[ct] = (f32x4){0.f,0.f,0.f,0.f};
  #pragma unroll
  for (int ct = 0; ct < 4; ++ct)
    #pragma unroll
    for (int s = 0; s < 2; ++s)
      acc[ct] = __builtin_amdgcn_mfma_f32_16x16x32_bf16(afr[s], bw[ct][s], acc[ct], 0,0,0);
  int node = nbase + w*2 + (quad>>1);
  #pragma unroll
  for (int ct = 0; ct < 4; ++ct){
    uint2 v;
    v.x = bf16rne(acc[ct][0]) | (bf16rne(acc[ct][1])<<16);
    v.y = bf16rne(acc[ct][2]) | (bf16rne(acc[ct][3])<<16);
    size_t o = ((size_t)node*64 + ct*16 + col)*8 + (quad&1)*4;
    *(uint2*)(Z2p + o) = v;
  }
}
// Batched aggregation + LN over all 7 t. One wave per node; lane = feature.
// Edge loop unrolled 4x: four independent 16B gathers in flight per wave.
__global__ __launch_bounds__(256) void k_agg_ln_all(const ushort* __restrict__ Z2p,
        const float* __restrict__ dinv, const int* __restrict__ rowptr,
        const uint2* __restrict__ e2,
        const float* __restrict__ bg2, const float* __restrict__ lng,
        const float* __restrict__ lnb, ushort* __restrict__ XT){
  int lane = threadIdx.x & 63, w = threadIdx.x >> 6;
  int i = blockIdx.x*4 + w;
  int beg = rowptr[i], end = rowptr[i+1];
  float di = dinv[i];
  float swt = di*di;
  const uint4* zp = (const uint4*)Z2p;
  float acc[7];
  {
    uint4 v = zp[(size_t)i*64 + lane];
    acc[0] = swt*bfu(v.x); acc[1] = swt*bfhi(v.x);
    acc[2] = swt*bfu(v.y); acc[3] = swt*bfhi(v.y);
    acc[4] = swt*bfu(v.z); acc[5] = swt*bfhi(v.z);
    acc[6] = swt*bfu(v.w);
  }
  int s = beg;
  for (; s + 4 <= end; s += 4){
    uint2 ea = e2[s],   eb = e2[s+1];
    uint2 ec = e2[s+2], ed = e2[s+3];
    uint4 va = zp[(size_t)ea.x*64 + lane];
    uint4 vb = zp[(size_t)eb.x*64 + lane];
    uint4 vc = zp[(size_t)ec.x*64 + lane];
    uint4 vd = zp[(size_t)ed.x*64 + lane];
    float wa = __uint_as_float(ea.y), wb = __uint_as_float(eb.y);
    float wc = __uint_as_float(ec.y), wd = __uint_as_float(ed.y);
    acc[0] = fmaf(wa, bfu(va.x),  acc[0]); acc[1] = fmaf(wa, bfhi(va.x), acc[1]);
    acc[2] = fmaf(wa, bfu(va.y),  acc[2]); acc[3] = fmaf(wa, bfhi(va.y), acc[3]);
    acc[4] = fmaf(wa, bfu(va.z),  acc[4]); acc[5] = fmaf(wa, bfhi(va.z), acc[5]);
    acc[6] = fmaf(wa, bfu(va.w),  acc[6]);
    acc[0] = fmaf(wb, bfu(vb.x),  acc[0]); acc[1] = fmaf(wb, bfhi(vb.x), acc[1]);
    acc[2] = fmaf(wb, bfu(vb.y),  acc[2]); acc[3] = fmaf(wb, bfhi(vb.y), acc[3]);
    acc[4] = fmaf(wb, bfu(vb.z),  acc[4]); acc[5] = fmaf(wb, bfhi(vb.z), acc[5]);
    acc[6] = fmaf(wb, bfu(vb.w),  acc[6]);
    acc[0] = fmaf(wc, bfu(vc.x),  acc[0]); acc[1] = fmaf(wc, bfhi(vc.x), acc[1]);
    acc[2] = fmaf(wc, bfu(vc.y),  acc[2]); acc[3] = fmaf(wc, bfhi(vc.y), acc[3]);
    acc[4] = fmaf(wc, bfu(vc.z),  acc[4]); acc[5] = fmaf(wc, bfhi(vc.z), acc[5]);
    acc[6] = fmaf(wc, bfu(vc.w),  acc[6]);
    acc[0] = fmaf(wd, bfu(vd.x),  acc[0]); acc[1] = fmaf(wd, bfhi(vd.x), acc[1]);
    acc[2] = fmaf(wd, bfu(vd.y),  acc[2]); acc[3] = fmaf(wd, bfhi(vd.y), acc[3]);
    acc[4] = fmaf(wd, bfu(vd.z),  acc[4]); acc[5] = fmaf(wd, bfhi(vd.z), acc[5]);
    acc[6] = fmaf(wd, bfu(vd.w),  acc[6]);
  }
  for (; s < end; ++s){
    uint2 e = e2[s];
    float wv = __uint_as_float(e.y);
    uint4 v = zp[(size_t)e.x*64 + lane];
    acc[0] = fmaf(wv, bfu(v.x),  acc[0]); acc[1] = fmaf(wv, bfhi(v.x), acc[1]);
    acc[2] = fmaf(wv, bfu(v.y),  acc[2]); acc[3] = fmaf(wv, bfhi(v.y), acc[3]);
    acc[4] = fmaf(wv, bfu(v.z),  acc[4]); acc[5] = fmaf(wv, bfhi(v.z), acc[5]);
    acc[6] = fmaf(wv, bfu(v.w),  acc[6]);
  }
  float b2 = bg2[lane], gl = lng[lane], bl = lnb[lane];
  #pragma unroll
  for (int t = 0; t < 7; ++t){
    float a = leaky01(acc[t] + b2);
    float sum = a;
    #pragma unroll
    for (int off = 32; off >= 1; off >>= 1) sum += __shfl_xor(sum, off, 64);
    float mu = sum * (1.f/64.f);
    float d = a - mu;
    float vs = d*d;
    #pragma unroll
    for (int off = 32; off >= 1; off >>= 1) vs += __shfl_xor(vs, off, 64);
    float rs = rsqrtf(vs*(1.f/64.f) + LN_EPS);
    XT[(size_t)t*NP*64 + (size_t)i*64 + lane] = (ushort)bf16rne(d*rs*gl + bl);
  }
}

// ---------------- LSTM (both layers) + MFMA heads — R14 champion body ----------------
__global__ __launch_bounds__(256) void k_lstm_heads(const ushort* __restrict__ xin,
        const uint4* __restrict__ WF, const float* __restrict__ BS,
        const uint4* __restrict__ WHF,
        const float* __restrict__ bm1, const float* __restrict__ bd1,
        const float* __restrict__ Wm2, const float* __restrict__ bm2,
        const float* __restrict__ Wd2, const float* __restrict__ bd2,
        float* __restrict__ out){
  __shared__ __align__(16) ushort XL[7][16][72];   // 15.75 KB (h0 planes)
  __shared__ __align__(16) ushort HB[2][16][72];   // 4.5 KB (L1 h ping-pong)
  int tid = threadIdx.x;
  int lane = tid & 63, cp = tid >> 6;
  int base = blockIdx.x*16;
  int col = lane & 15, quad = lane >> 4;
  bf16x8 hfr[2];
  for (int L = 0; L < 2; ++L){
    bf16x8 bwi[4][2], bwh[4][2];
    const uint4* wf = WF + L*4096;
    #pragma unroll
    for (int g = 0; g < 4; ++g){
      int ct = cp + 4*g;
      #pragma unroll
      for (int s = 0; s < 2; ++s){
        uint4 wi = wf[((ct*2+s)*2+0)*64 + lane];
        uint4 wh = wf[((ct*2+s)*2+1)*64 + lane];
        bwi[g][s] = *(bf16x8*)&wi;
        bwh[g][s] = *(bf16x8*)&wh;
      }
    }
    float bias[4];
    #pragma unroll
    for (int g = 0; g < 4; ++g) bias[g] = BS[L*256 + (cp + 4*g)*16 + col];
    f32x4 cst = (f32x4){0.f,0.f,0.f,0.f};
    hfr[0] = (bf16x8){0,0,0,0,0,0,0,0};
    hfr[1] = (bf16x8){0,0,0,0,0,0,0,0};

    for (int t = 0; t < 7; ++t){
      bf16x8 ax[2];
      if (L == 0){
        #pragma unroll
        for (int s = 0; s < 2; ++s)
          ax[s] = *(const bf16x8*)(xin + (size_t)t*NP*64
                          + (size_t)(base + col)*64 + s*32 + quad*8);
      } else {
        #pragma unroll
        for (int s = 0; s < 2; ++s)
          ax[s] = *(const bf16x8*)&XL[t][col][s*32 + quad*8];
      }
      f32x4 acc[4];
      #pragma unroll
      for (int g = 0; g < 4; ++g){
        float b = bias[g];
        acc[g] = (f32x4){b,b,b,b};
      }
      #pragma unroll
      for (int g = 0; g < 4; ++g){
        #pragma unroll
        for (int s = 0; s < 2; ++s){
          acc[g] = __builtin_amdgcn_mfma_f32_16x16x32_bf16(ax[s], bwi[g][s], acc[g], 0,0,0);
          acc[g] = __builtin_amdgcn_mfma_f32_16x16x32_bf16(hfr[s], bwh[g][s], acc[g], 0,0,0);
        }
      }
      ushort (*dstp)[72] = (L == 0) ? XL[t] : HB[t & 1];
      #pragma unroll
      for (int r = 0; r < 4; ++r){
        float ig = fastrcp(1.f + exp2fast(acc[0][r]));
        float fg = fastrcp(1.f + exp2fast(acc[1][r]));
        float gg = fmaf(-2.f, fastrcp(1.f + exp2fast(acc[2][r])), 1.f);
        float og = fastrcp(1.f + exp2fast(acc[3][r]));
        float cn = fmaf(fg, cst[r], ig*gg);
        cst[r] = cn;
        float tc = fmaf(-2.f, fastrcp(1.f + exp2fast(TANH_SC*cn)), 1.f);
        dstp[quad*4 + r][cp*16 + col] = (ushort)bf16rne(og*tc);
      }
      __syncthreads();
      hfr[0] = *(const bf16x8*)&dstp[col][quad*8];
      hfr[1] = *(const bf16x8*)&dstp[col][32 + quad*8];
    }
  }
  // ---- heads: hfr = final h1 A-frags. First layer (64->48) via MFMA. ----
  float* SH1 = (float*)&XL[0][0][0];   // planes 0-1 dead; [16][52] = 3.3 KB
  if (cp < 3){
    uint4 w0 = WHF[(cp*2+0)*64 + lane];
    uint4 w1 = WHF[(cp*2+1)*64 + lane];
    f32x4 hacc = (f32x4){0.f,0.f,0.f,0.f};
    hacc = __builtin_amdgcn_mfma_f32_16x16x32_bf16(hfr[0], *(bf16x8*)&w0, hacc, 0,0,0);
    hacc = __builtin_amdgcn_mfma_f32_16x16x32_bf16(hfr[1], *(bf16x8*)&w1, hacc, 0,0,0);
    #pragma unroll
    for (int r = 0; r < 4; ++r){
      int c = cp*16 + col;
      float b = (cp < 2) ? bm1[c] : bd1[col];
      float v = hacc[r] + b;
      v = (cp < 2) ? leaky01(v) : fmaxf(v, 0.f);
      SH1[(quad*4 + r)*52 + cp*16 + col] = v;
    }
  }
  __syncthreads();
  // ---- second layer: 16 threads/node, shfl-reduce over the 16-lane group ----
  int node = tid >> 4, sub = tid & 15;
  int gn = base + node;
  float m1a = SH1[node*52 + sub];
  float m1b = SH1[node*52 + 16 + sub];
  float d1v = SH1[node*52 + 32 + sub];
  float4 wa = *(const float4*)&Wm2[sub*4];
  float4 wb = *(const float4*)&Wm2[(sub+16)*4];
  float4 wc = *(const float4*)&Wd2[sub*4];
  float pm0 = m1a*wa.x + m1b*wb.x, pm1 = m1a*wa.y + m1b*wb.y;
  float pm2 = m1a*wa.z + m1b*wb.z, pm3 = m1a*wa.w + m1b*wb.w;
  float pd0 = d1v*wc.x, pd1 = d1v*wc.y, pd2 = d1v*wc.z, pd3 = d1v*wc.w;
  #pragma unroll
  for (int off = 1; off < 16; off <<= 1){
    pm0 += __shfl_xor(pm0, off, 16); pm1 += __shfl_xor(pm1, off, 16);
    pm2 += __shfl_xor(pm2, off, 16); pm3 += __shfl_xor(pm3, off, 16);
    pd0 += __shfl_xor(pd0, off, 16); pd1 += __shfl_xor(pd1, off, 16);
    pd2 += __shfl_xor(pd2, off, 16); pd3 += __shfl_xor(pd3, off, 16);
  }
  if (sub < 4 && gn < NN){
    float mo = (sub==0)?pm0:(sub==1)?pm1:(sub==2)?pm2:pm3;
    float dv = (sub==0)?pd0:(sub==1)?pd1:(sub==2)?pd2:pd3;
    mo += bm2[sub]; dv += bd2[sub];
    out[(size_t)gn*4 + sub] = fmaxf(mo, 0.f) + 1e-4f;
    out[(size_t)NN*4 + (size_t)gn*4 + sub] = dv;
  }
}

extern "C" void kernel_launch(void* const* d_in, const int* in_sizes, int n_in,
                              void* d_out, int out_size, void* d_ws, size_t ws_size,
                              hipStream_t stream){
  const float* x    = (const float*)d_in[0];
  const int*   eidx = (const int*)d_in[1];
  const float* ew   = (const float*)d_in[2];
  const float* Wg1  = (const float*)d_in[3];
  const float* bg1  = (const float*)d_in[4];
  const float* Wg2  = (const float*)d_in[5];
  const float* bg2  = (const float*)d_in[6];
  const float* lng  = (const float*)d_in[7];
  const float* lnb  = (const float*)d_in[8];
  const float* Wih0 = (const float*)d_in[9];
  const float* Whh0 = (const float*)d_in[10];
  const float* bih0 = (const float*)d_in[11];
  const float* bhh0 = (const float*)d_in[12];
  const float* Wih1 = (const float*)d_in[13];
  const float* Whh1 = (const float*)d_in[14];
  const float* bih1 = (const float*)d_in[15];
  const float* bhh1 = (const float*)d_in[16];
  const float* Wm1  = (const float*)d_in[17];
  const float* bm1  = (const float*)d_in[18];
  const float* Wm2  = (const float*)d_in[19];
  const float* bm2  = (const float*)d_in[20];
  const float* Wd1  = (const float*)d_in[21];
  const float* bd1  = (const float*)d_in[22];
  const float* Wd2  = (const float*)d_in[23];
  const float* bd2  = (const float*)d_in[24];
  const int* src = eidx;
  const int* dst = eidx + EE;
  float* out = (float*)d_out;

  char* p = (char*)d_ws;
  auto alloc = [&](size_t bytes)->char*{ char* r = p; p += (bytes + 255) & ~(size_t)255; return r; };
  float*  deg     = (float*)alloc((size_t)NN*4);       // becomes dinv
  int*    counts  = (int*)  alloc((size_t)NN*4);
  int*    rowptr  = (int*)  alloc((size_t)(NN+1)*4);
  int*    cursor  = (int*)  alloc((size_t)NN*4);
  int*    locincl = (int*)  alloc((size_t)NN*4);
  int*    bsum    = (int*)  alloc((size_t)256*4);
  uint2*  e2      = (uint2*)alloc((size_t)EE*8);
  uint4*  WF      = (uint4*)alloc((size_t)2*4096*16);
  uint4*  WG2F    = (uint4*)alloc((size_t)512*16);
  uint4*  WHF     = (uint4*)alloc((size_t)384*16);
  float*  BS      = (float*)alloc((size_t)2*256*4);
  ushort* xb      = (ushort*)alloc((size_t)NN*49*2);
  ushort* XT      = (ushort*)alloc((size_t)TT*NP*64*2);
  float*  AX      = (float*)alloc((size_t)NN*49*4);
  ushort* Z2p     = (ushort*)alloc((size_t)NN*64*8*2);

  int xblocks = (NN*49 + 255)/256;                 // 9571
  k_prep_all<<<234 + xblocks, 256, 0, stream>>>(Wih0, Whh0, Wih1, Whh1, Wg2,
      bih0, bhh0, bih1, bhh1, Wm1, Wd1, x, WF, WG2F, WHF, BS, xb, deg, counts);
  k_edge_count<<<(EE+255)/256, 256, 0, stream>>>(src, dst, ew, deg, counts);
  k_scan_blk<<<196, 256, 0, stream>>>(counts, locincl, bsum, deg);
  k_scan_fix<<<196, 256, 0, stream>>>(locincl, bsum, counts, rowptr, cursor);
  k_scatter<<<(EE+255)/256, 256, 0, stream>>>(src, dst, ew, deg, cursor, e2);
  k_agg_x<<<NN/4, 256, 0, stream>>>(xb, deg, rowptr, e2, AX);
  k_gcn2_mfma<<<NN/8, 256, 0, stream>>>(AX, Wg1, bg1, WG2F, Z2p);
  k_agg_ln_all<<<NN/4, 256, 0, stream>>>(Z2p, deg, rowptr, e2, bg2, lng, lnb, XT);
  k_lstm_heads<<<NP/16, 256, 0, stream>>>(XT, WF, BS, WHF,
      bm1, bd1, Wm2, bm2, Wd2, bd2, out);
}